// Round 1
// baseline (6637.900 us; speedup 1.0000x reference)
//
#include <hip/hip_runtime.h>
#include <hip/hip_bf16.h>
#include <hip/hip_cooperative_groups.h>
#include <math.h>

// ---------------------------------------------------------------------------
// WaveNet inference, fp32, right-aligned suffix computation.
// Derivations (verified earlier, absmax 2.4e-4):
//  - dilate() batch-folding == time-domain dilated 2-tap conv: out[t] uses
//    taps X[t], X[t+d]; residual adds X[t+d].
//  - x_skip is OVERWRITTEN each layer -> only layer 39's skip matters, and
//    its input is h = tanh*sigmoid (BEFORE the residual conv).
//  - output needs only the trailing 4096+4092=8188 samples of start conv.
// Round 4 (this round): all 40 layer launches fused into ONE persistent
// cooperative kernel (grid-wide sync between layers). 2 timesteps/thread
// (t and t+4096): halves scalar weight-load pressure per FMA, doubles load
// ILP, halves wave count. 512 blocks of (64,4) = 2 blocks/CU guaranteed
// co-resident (VGPR<=256, LDS 16KB). Tile0 (t<4096) always active since
// min Tout==4096; tile1 clamped/guarded and dead at layer 39.
// ---------------------------------------------------------------------------

#define TS   8192
#define T0   8188
#define NB   8
#define RCH  32
#define CLS  256
#define TOUT 4096

// workspace layout (float offsets)
#define OFF_WBLOB 0                      // 40 * 5120  (wf[ic][k][oc], wg, wr[ic][oc])
#define OFF_ST    204800                 // start_w^T  [ic][oc]
#define OFF_SK    212992                 // skip_w[39]^T [dc][sc]
#define OFF_E1T   221184                 // end1^T [sc][ec]
#define OFF_E2T   286720                 // end2^T [ec][cc]
#define OFF_XA    352256                 // NB*RCH*TS
#define OFF_XB    (OFF_XA + NB*RCH*TS)
#define OFF_H1    (OFF_XB + NB*RCH*TS)   // NB*256*TOUT
#define OFF_E1    (OFF_H1 + NB*256*TOUT)

__device__ __forceinline__ float tanh_fast(float x) {
    float e = __expf(2.0f * x);
    return 1.0f - 2.0f / (e + 1.0f);
}
__device__ __forceinline__ float sigmoid_fast(float x) {
    return 1.0f / (1.0f + __expf(-x));
}

// ---------------------------------------------------------------------------
__global__ void repack_kernel(const float* __restrict__ start_w,
                              const float* __restrict__ filter_w,
                              const float* __restrict__ gate_w,
                              const float* __restrict__ residual_w,
                              const float* __restrict__ skip_w,
                              const float* __restrict__ end1_w,
                              const float* __restrict__ end2_w,
                              float* __restrict__ ws) {
    int id = blockIdx.x * 256 + threadIdx.x;
    if (id < 204800) {
        int l = id / 5120, r = id % 5120;
        float v;
        if (r < 4096) {                      // wf then wg: [ic][k][oc]
            const float* src = (r < 2048) ? filter_w : gate_w;
            int rr = r & 2047;
            int ic = rr >> 6, k = (rr >> 5) & 1, oc = rr & 31;
            v = src[((l * 32 + oc) * 32 + ic) * 2 + k];
        } else {                             // wr: [ic][oc]
            int rr = r - 4096;
            int ic = rr >> 5, oc = rr & 31;
            v = residual_w[(l * 32 + oc) * 32 + ic];
        }
        ws[OFF_WBLOB + id] = v;
    } else if (id < 204800 + 8192) {
        int r = id - 204800;
        int ic = r >> 5, oc = r & 31;
        ws[OFF_ST + r] = start_w[oc * 256 + ic];
    } else if (id < 212992 + 8192) {
        int r = id - 212992;
        int dc = r >> 8, sc = r & 255;
        ws[OFF_SK + r] = skip_w[(39 * 256 + sc) * 32 + dc];
    } else if (id < 221184 + 65536) {
        int r = id - 221184;
        int sc = r >> 8, ec = r & 255;
        ws[OFF_E1T + r] = end1_w[ec * 256 + sc];
    } else if (id < 286720 + 65536) {
        int r = id - 286720;
        int ec = r >> 8, cc = r & 255;
        ws[OFF_E2T + r] = end2_w[cc * 256 + ec];
    }
}

// ---------------------------------------------------------------------------
// start conv, 16 outputs/thread
__global__ __launch_bounds__(256) void start_kernel(const float* __restrict__ xin,
                                                    const float* __restrict__ st,
                                                    float* __restrict__ xout) {
    int t = blockIdx.x * 256 + threadIdx.x;
    int og = blockIdx.y;                     // 0..1 (16 oc each)
    int b = blockIdx.z;
    if (t >= T0) return;
    const float* xi = xin + (size_t)b * 256 * 16384 + (16384 - T0) + t;
    const float* wb = st + og * 16;
    float acc[16];
#pragma unroll
    for (int c = 0; c < 16; c++) acc[c] = 0.f;
#pragma unroll 4
    for (int ic = 0; ic < 256; ic++) {
        float xv = xi[ic * 16384];
        const float* w = wb + ic * 32;
#pragma unroll
        for (int c = 0; c < 16; c++) acc[c] = fmaf(w[c], xv, acc[c]);
    }
    float* xo = xout + ((size_t)(b * RCH) + og * 16) * TS + t;
#pragma unroll
    for (int c = 0; c < 16; c++) xo[c * TS] = acc[c];
}

// ---------------------------------------------------------------------------
// ALL 40 WaveNet layers in one persistent cooperative kernel.
// Grid: 512 blocks = 64 t-blocks x 8 batches, block (64,4).
// Each thread: 2 timesteps (t0 in [0,4096), t1 = t0+4096), 8 oc (threadIdx.y).
// Weights via wave-uniform scalar loads, shared across both tiles.
__global__ __launch_bounds__(256, 2) void layers_kernel(float* __restrict__ bufA,
                                                        float* __restrict__ bufB,
                                                        const float* __restrict__ wblob) {
    cooperative_groups::grid_group gg = cooperative_groups::this_grid();
    __shared__ float hs[2][32][64];
    const int tx  = threadIdx.x;                               // lane = timestep
    const int cgq = __builtin_amdgcn_readfirstlane(threadIdx.y);
    const int b   = blockIdx.x >> 6;                           // batch 0..7
    const int tb  = blockIdx.x & 63;                           // 0..63
    const int t0  = tb * 64 + tx;                              // always < 4096

    float* bin  = bufA;
    float* bout = bufB;
    int Tin = T0;

    for (int l = 0; l < 40; ++l) {
        const int d    = 1 << (l % 10);
        const int Tout = Tin - d;                              // >= 4096 always
        const int t1   = t0 + 4096;
        const bool act1 = (t1 < Tout);
        const int t1c  = act1 ? t1 : (Tout - 1);               // clamp: stays in-bounds

        const float* wf = wblob + (size_t)l * 5120 + cgq * 8;  // wf[ic*64 + k*32 + oc8]
        const float* wg = wf + 2048;
        const float* wr = wf + 4096;                           // wr[ic*32 + oc8]

        const float* x0  = bin + (size_t)b * (RCH * TS) + t0;
        const float* x1  = bin + (size_t)b * (RCH * TS) + t1c;
        const float* x0d = x0 + d;
        const float* x1d = x1 + d;

        float f0[8], g0[8], f1[8], g1[8];
#pragma unroll
        for (int j = 0; j < 8; j++) { f0[j] = 0.f; g0[j] = 0.f; f1[j] = 0.f; g1[j] = 0.f; }

#pragma unroll 4
        for (int ic = 0; ic < 32; ic++) {
            const float a0 = x0[ic * TS];
            const float c0 = x0d[ic * TS];
            const float a1 = x1[ic * TS];
            const float c1 = x1d[ic * TS];
            const float* w0 = wf + ic * 64;
            const float* w1 = wg + ic * 64;
#pragma unroll
            for (int j = 0; j < 8; j++) {
                const float wa = w0[j], wc = w0[32 + j];
                f0[j] = fmaf(wa, a0, f0[j]);
                f1[j] = fmaf(wa, a1, f1[j]);
                f0[j] = fmaf(wc, c0, f0[j]);
                f1[j] = fmaf(wc, c1, f1[j]);
            }
#pragma unroll
            for (int j = 0; j < 8; j++) {
                const float wa = w1[j], wc = w1[32 + j];
                g0[j] = fmaf(wa, a0, g0[j]);
                g1[j] = fmaf(wa, a1, g1[j]);
                g0[j] = fmaf(wc, c0, g0[j]);
                g1[j] = fmaf(wc, c1, g1[j]);
            }
        }

        if (l == 39) {
            // last layer: only h = tanh*sigmoid is consumed; tile1 dead (Tout==4096)
            float* xo0 = bout + ((size_t)b * RCH + cgq * 8) * TS + t0;
#pragma unroll
            for (int j = 0; j < 8; j++)
                xo0[j * TS] = tanh_fast(f0[j]) * sigmoid_fast(g0[j]);
            // no sync needed: kernel completion orders vs. skip_kernel
        } else {
#pragma unroll
            for (int j = 0; j < 8; j++) {
                hs[0][cgq * 8 + j][tx] = tanh_fast(f0[j]) * sigmoid_fast(g0[j]);
                hs[1][cgq * 8 + j][tx] = tanh_fast(f1[j]) * sigmoid_fast(g1[j]);
            }
            __syncthreads();

            float r0[8], r1[8];
#pragma unroll
            for (int j = 0; j < 8; j++) {                      // residual = X[t+d]
                r0[j] = x0d[(cgq * 8 + j) * TS];
                r1[j] = x1d[(cgq * 8 + j) * TS];
            }
#pragma unroll 4
            for (int ic = 0; ic < 32; ic++) {
                const float h0 = hs[0][ic][tx];
                const float h1 = hs[1][ic][tx];
                const float* w = wr + ic * 32;
#pragma unroll
                for (int j = 0; j < 8; j++) {
                    r0[j] = fmaf(w[j], h0, r0[j]);
                    r1[j] = fmaf(w[j], h1, r1[j]);
                }
            }
            float* xo0 = bout + ((size_t)b * RCH + cgq * 8) * TS + t0;
#pragma unroll
            for (int j = 0; j < 8; j++) xo0[j * TS] = r0[j];
            if (act1) {
                float* xo1 = bout + ((size_t)b * RCH + cgq * 8) * TS + t1;
#pragma unroll
                for (int j = 0; j < 8; j++) xo1[j * TS] = r1[j];
            }

            float* tmp = bin; bin = bout; bout = tmp;
            Tin = Tout;
            __threadfence();      // cross-XCD: push bout out of local L2
            gg.sync();
            __threadfence();      // cross-XCD: drop stale lines before reading new bin
        }
    }
}

// ---------------------------------------------------------------------------
// skip conv + relu, 32 outputs/thread
__global__ __launch_bounds__(256) void skip_kernel(const float* __restrict__ xin,
                                                   const float* __restrict__ sk,
                                                   float* __restrict__ h1) {
    int t = blockIdx.x * 256 + threadIdx.x;
    int sg = blockIdx.y;                     // 8 groups of 32
    int b = blockIdx.z;
    const float* xi = xin + (size_t)(b * RCH) * TS + t;
    const float* wb = sk + sg * 32;
    float acc[32];
#pragma unroll
    for (int j = 0; j < 32; j++) acc[j] = 0.f;
#pragma unroll 4
    for (int dc = 0; dc < 32; dc++) {
        float xv = xi[dc * TS];
        const float* w = wb + dc * 256;
#pragma unroll
        for (int j = 0; j < 32; j++) acc[j] = fmaf(w[j], xv, acc[j]);
    }
    float* ho = h1 + ((size_t)(b * 256) + sg * 32) * TOUT + t;
#pragma unroll
    for (int j = 0; j < 32; j++) ho[j * TOUT] = fmaxf(acc[j], 0.f);
}

// end1 + bias + relu, 32 outputs/thread
__global__ __launch_bounds__(256) void end1_kernel(const float* __restrict__ h1,
                                                   const float* __restrict__ e1t,
                                                   const float* __restrict__ b1,
                                                   float* __restrict__ e1) {
    int t = blockIdx.x * 256 + threadIdx.x;
    int eg = blockIdx.y;                     // 8 groups of 32
    int b = blockIdx.z;
    const float* hp = h1 + (size_t)(b * 256) * TOUT + t;
    const float* wb = e1t + eg * 32;
    float acc[32];
#pragma unroll
    for (int j = 0; j < 32; j++) acc[j] = b1[eg * 32 + j];
#pragma unroll 4
    for (int sc = 0; sc < 256; sc++) {
        float xv = hp[sc * TOUT];
        const float* w = wb + sc * 256;
#pragma unroll
        for (int j = 0; j < 32; j++) acc[j] = fmaf(w[j], xv, acc[j]);
    }
    float* ep = e1 + ((size_t)(b * 256) + eg * 32) * TOUT + t;
#pragma unroll
    for (int j = 0; j < 32; j++) ep[j * TOUT] = fmaxf(acc[j], 0.f);
}

// end2 + bias, transposed store, 32 outputs/thread
__global__ __launch_bounds__(256) void end2_kernel(const float* __restrict__ e1,
                                                   const float* __restrict__ e2t,
                                                   const float* __restrict__ b2,
                                                   float* __restrict__ out) {
    int t = blockIdx.x * 256 + threadIdx.x;
    int cg = blockIdx.y;                     // 8 groups of 32
    int b = blockIdx.z;
    const float* ep = e1 + (size_t)(b * 256) * TOUT + t;
    const float* wb = e2t + cg * 32;
    float acc[32];
#pragma unroll
    for (int j = 0; j < 32; j++) acc[j] = b2[cg * 32 + j];
#pragma unroll 4
    for (int ec = 0; ec < 256; ec++) {
        float xv = ep[ec * TOUT];
        const float* w = wb + ec * 256;
#pragma unroll
        for (int j = 0; j < 32; j++) acc[j] = fmaf(w[j], xv, acc[j]);
    }
    float* op = out + ((size_t)(b * TOUT + t)) * CLS + cg * 32;
#pragma unroll
    for (int j = 0; j < 8; j++)
        ((float4*)op)[j] = make_float4(acc[4*j], acc[4*j+1], acc[4*j+2], acc[4*j+3]);
}

// ---------------------------------------------------------------------------
extern "C" void kernel_launch(void* const* d_in, const int* in_sizes, int n_in,
                              void* d_out, int out_size, void* d_ws, size_t ws_size,
                              hipStream_t stream) {
    const float* x_input    = (const float*)d_in[0];
    const float* start_w    = (const float*)d_in[1];
    const float* filter_w   = (const float*)d_in[2];
    const float* gate_w     = (const float*)d_in[3];
    const float* residual_w = (const float*)d_in[4];
    const float* skip_w     = (const float*)d_in[5];
    const float* end1_w     = (const float*)d_in[6];
    const float* end1_b     = (const float*)d_in[7];
    const float* end2_w     = (const float*)d_in[8];
    const float* end2_b     = (const float*)d_in[9];
    float* ws  = (float*)d_ws;
    float* out = (float*)d_out;

    repack_kernel<<<dim3((352256 + 255) / 256), 256, 0, stream>>>(
        start_w, filter_w, gate_w, residual_w, skip_w, end1_w, end2_w, ws);

    start_kernel<<<dim3(32, 2, NB), 256, 0, stream>>>(
        x_input, ws + OFF_ST, ws + OFF_XA);

    // all 40 layers, one cooperative launch. 39 swaps -> final h in OFF_XA.
    {
        float* bufA = ws + OFF_XA;
        float* bufB = ws + OFF_XB;
        const float* wb = ws + OFF_WBLOB;
        void* args[3] = { &bufA, &bufB, &wb };
        hipLaunchCooperativeKernel(layers_kernel, dim3(512), dim3(64, 4),
                                   args, 0, stream);
    }

    skip_kernel<<<dim3(16, 8, NB), 256, 0, stream>>>(ws + OFF_XA, ws + OFF_SK, ws + OFF_H1);
    end1_kernel<<<dim3(16, 8, NB), 256, 0, stream>>>(ws + OFF_H1, ws + OFF_E1T, end1_b, ws + OFF_E1);
    end2_kernel<<<dim3(16, 8, NB), 256, 0, stream>>>(ws + OFF_E1, ws + OFF_E2T, end2_b, out);
}

// Round 2
// 2073.187 us; speedup vs baseline: 3.2018x; 3.2018x over previous
//
#include <hip/hip_runtime.h>
#include <math.h>

// ---------------------------------------------------------------------------
// WaveNet inference, fp32, right-aligned suffix computation.
// Round 5: 40 per-layer launches -> 8 fused launches (no cooperative sync;
// round-4 cooperative grid.sync measured ~160us/sync, VALUBusy 4.7% -> dead end).
//  - head_kernel: 5 layers d=1..16 fused; halo=31; block owns 256 outputs x
//    32 ch in LDS (32x288), thread owns 1 timestep x 32 ch -> h thread-local.
//  - tail_kernel: 5 layers d=32..512 preserve t mod 32 -> 32 independent
//    subsequences (sub-dilations 1..16); block owns (batch, residue) whole
//    subsequence (<=255) in LDS. No halo.
//  - transpose staging buffer Xsub[b][ch][r][i] (reuses old XB space):
//    head stores scattered / tail loads coalesced; tail stores scattered
//    back to normal layout / head+skip load coalesced.
// Chain: 8188 -h-> 8157 -t-> 7165 -h-> 7134 -t-> 6142 -h-> 6111 -t-> 5119
//        -h-> 5088 -t-> 4096.  Layer 39 (last tail, s=4) emits h only.
// ---------------------------------------------------------------------------

#define TS   8192
#define T0   8188
#define NB   8
#define RCH  32
#define CLS  256
#define TOUT 4096

// workspace layout (float offsets)
#define OFF_WBLOB 0                      // 40 * 5120  (wf[ic][k][oc], wg, wr[ic][oc])
#define OFF_ST    204800                 // start_w^T  [ic][oc]
#define OFF_SK    212992                 // skip_w[39]^T [dc][sc]
#define OFF_E1T   221184                 // end1^T [sc][ec]
#define OFF_E2T   286720                 // end2^T [ec][cc]
#define OFF_XA    352256                 // NB*RCH*TS   (normal layout)
#define OFF_XSUB  (OFF_XA + NB*RCH*TS)   // NB*32*32*256 (sub layout, == XB size)
#define OFF_H1    (OFF_XSUB + NB*RCH*TS) // NB*256*TOUT
#define OFF_E1    (OFF_H1 + NB*256*TOUT)

__device__ __forceinline__ float tanh_fast(float x) {
    float e = __expf(2.0f * x);
    return 1.0f - 2.0f / (e + 1.0f);
}
__device__ __forceinline__ float sigmoid_fast(float x) {
    return 1.0f / (1.0f + __expf(-x));
}

// ---------------------------------------------------------------------------
__global__ void repack_kernel(const float* __restrict__ start_w,
                              const float* __restrict__ filter_w,
                              const float* __restrict__ gate_w,
                              const float* __restrict__ residual_w,
                              const float* __restrict__ skip_w,
                              const float* __restrict__ end1_w,
                              const float* __restrict__ end2_w,
                              float* __restrict__ ws) {
    int id = blockIdx.x * 256 + threadIdx.x;
    if (id < 204800) {
        int l = id / 5120, r = id % 5120;
        float v;
        if (r < 4096) {                      // wf then wg: [ic][k][oc]
            const float* src = (r < 2048) ? filter_w : gate_w;
            int rr = r & 2047;
            int ic = rr >> 6, k = (rr >> 5) & 1, oc = rr & 31;
            v = src[((l * 32 + oc) * 32 + ic) * 2 + k];
        } else {                             // wr: [ic][oc]
            int rr = r - 4096;
            int ic = rr >> 5, oc = rr & 31;
            v = residual_w[(l * 32 + oc) * 32 + ic];
        }
        ws[OFF_WBLOB + id] = v;
    } else if (id < 204800 + 8192) {
        int r = id - 204800;
        int ic = r >> 5, oc = r & 31;
        ws[OFF_ST + r] = start_w[oc * 256 + ic];
    } else if (id < 212992 + 8192) {
        int r = id - 212992;
        int dc = r >> 8, sc = r & 255;
        ws[OFF_SK + r] = skip_w[(39 * 256 + sc) * 32 + dc];
    } else if (id < 221184 + 65536) {
        int r = id - 221184;
        int sc = r >> 8, ec = r & 255;
        ws[OFF_E1T + r] = end1_w[ec * 256 + sc];
    } else if (id < 286720 + 65536) {
        int r = id - 286720;
        int ec = r >> 8, cc = r & 255;
        ws[OFF_E2T + r] = end2_w[cc * 256 + ec];
    }
}

// ---------------------------------------------------------------------------
// start conv, 16 outputs/thread
__global__ __launch_bounds__(256) void start_kernel(const float* __restrict__ xin,
                                                    const float* __restrict__ st,
                                                    float* __restrict__ xout) {
    int t = blockIdx.x * 256 + threadIdx.x;
    int og = blockIdx.y;                     // 0..1 (16 oc each)
    int b = blockIdx.z;
    if (t >= T0) return;
    const float* xi = xin + (size_t)b * 256 * 16384 + (16384 - T0) + t;
    const float* wb = st + og * 16;
    float acc[16];
#pragma unroll
    for (int c = 0; c < 16; c++) acc[c] = 0.f;
#pragma unroll 4
    for (int ic = 0; ic < 256; ic++) {
        float xv = xi[ic * 16384];
        const float* w = wb + ic * 32;
#pragma unroll
        for (int c = 0; c < 16; c++) acc[c] = fmaf(w[c], xv, acc[c]);
    }
    float* xo = xout + ((size_t)(b * RCH) + og * 16) * TS + t;
#pragma unroll
    for (int c = 0; c < 16; c++) xo[c * TS] = acc[c];
}

// ---------------------------------------------------------------------------
// One timestep, one layer: all 32 channels in-thread. Weights are wave-uniform
// (s_load). oc processed in 4 groups of 8 to cap SGPR/VGPR pressure; h[32]
// thread-local so the residual 1x1 conv needs no cross-thread exchange.
template<int LDSW>
__device__ __forceinline__ void layer_slot(const float* Xs, int p, int d,
                                           const float* __restrict__ wf,
                                           const float* __restrict__ wg,
                                           const float* __restrict__ wr,
                                           float out[32], bool h_only) {
    float h[32];
#pragma unroll
    for (int grp = 0; grp < 4; ++grp) {
        float f[8], g[8];
#pragma unroll
        for (int j = 0; j < 8; ++j) { f[j] = 0.f; g[j] = 0.f; }
#pragma unroll 4
        for (int ic = 0; ic < 32; ++ic) {
            const float a = Xs[ic * LDSW + p];
            const float c = Xs[ic * LDSW + p + d];
            const float* w0 = wf + ic * 64 + grp * 8;
            const float* w1 = wg + ic * 64 + grp * 8;
#pragma unroll
            for (int j = 0; j < 8; ++j) {
                f[j] = fmaf(w0[j],      a, f[j]);
                f[j] = fmaf(w0[32 + j], c, f[j]);
                g[j] = fmaf(w1[j],      a, g[j]);
                g[j] = fmaf(w1[32 + j], c, g[j]);
            }
        }
#pragma unroll
        for (int j = 0; j < 8; ++j)
            h[grp * 8 + j] = tanh_fast(f[j]) * sigmoid_fast(g[j]);
    }
    if (h_only) {
#pragma unroll
        for (int oc = 0; oc < 32; ++oc) out[oc] = h[oc];
        return;
    }
#pragma unroll
    for (int grp = 0; grp < 4; ++grp) {
        float r[8];
#pragma unroll
        for (int j = 0; j < 8; ++j)                 // residual tap X[t+d]
            r[j] = Xs[(grp * 8 + j) * LDSW + p + d];
        const float* w2 = wr + grp * 8;
#pragma unroll 4
        for (int ic = 0; ic < 32; ++ic) {
            const float hv = h[ic];
#pragma unroll
            for (int j = 0; j < 8; ++j)
                r[j] = fmaf(w2[ic * 32 + j], hv, r[j]);
        }
#pragma unroll
        for (int j = 0; j < 8; ++j) out[grp * 8 + j] = r[j];
    }
}

// ---------------------------------------------------------------------------
// HEAD: 5 fused layers d=1,2,4,8,16 (halo 31). Block = (chunk of 256 output
// timesteps) x batch. LDS tile 32ch x 288. In-place LDS update per layer:
// all reads pre-barrier (residual tap read inside layer_slot), writes after.
// Extra positions 256..286 (sb0 only) spread 1-per-8-threads across waves.
__global__ __launch_bounds__(256) void head_kernel(const float* __restrict__ X,
                                                   float* __restrict__ Xsub,
                                                   const float* __restrict__ wl0,
                                                   int Tin) {
    __shared__ float Xs[32 * 288];
    const int tid = threadIdx.x;
    const int b   = blockIdx.y;
    const int c0  = blockIdx.x * 256;
    const int Lw  = min(288, Tin - c0);

    const float* xb = X + (size_t)b * (RCH * TS) + c0;
    for (int idx = tid; idx < 32 * 288; idx += 256) {
        int ch = idx / 288, p = idx - ch * 288;
        if (p < Lw) Xs[ch * 288 + p] = xb[(size_t)ch * TS + p];
    }
    __syncthreads();

    int w = Lw;
    for (int s = 0; s < 5; ++s) {
        const int d  = 1 << s;
        const int nw = w - d;
        const float* wf = wl0 + s * 5120;

        float out0[32];
        const bool a0 = (tid < nw);
        if (a0) layer_slot<288>(Xs, tid, d, wf, wf + 2048, wf + 4096, out0, false);

        float out1[32];
        const int  p1 = 256 + (tid >> 3);
        const bool a1 = (nw > 256) && ((tid & 7) == 0) && (p1 < nw);
        if (nw > 256) {
            if (a1) layer_slot<288>(Xs, p1, d, wf, wf + 2048, wf + 4096, out1, false);
        }
        __syncthreads();
        if (a0) {
#pragma unroll
            for (int oc = 0; oc < 32; ++oc) Xs[oc * 288 + tid] = out0[oc];
        }
        if (a1) {
#pragma unroll
            for (int oc = 0; oc < 32; ++oc) Xs[oc * 288 + p1] = out1[oc];
        }
        __syncthreads();
        w = nw;
    }

    // store to sub layout [b][oc][r][i]; scattered 4B stores (through L2)
    const int ow = min(256, w);
    if (tid < ow) {
        const int t = c0 + tid, rr = t & 31, ii = t >> 5;
        float* xs = Xsub + ((size_t)(b * 32) * 32 + rr) * 256 + ii;
#pragma unroll
        for (int oc = 0; oc < 32; ++oc)
            xs[(size_t)oc * (32 * 256)] = Xs[oc * 288 + tid];
    }
}

// ---------------------------------------------------------------------------
// TAIL: 5 fused layers d=32..512 == sub-dilations 1..16 on 32 independent
// residue subsequences. Block = (residue r, batch). Whole subsequence
// (<=255) in LDS; no halo. Loads coalesced from Xsub; stores scattered back
// to normal layout. last: layer s=4 (l==39) writes h (skip-conv input).
__global__ __launch_bounds__(256) void tail_kernel(const float* __restrict__ Xsub,
                                                   float* __restrict__ X,
                                                   const float* __restrict__ wl5,
                                                   int Tin, int last) {
    __shared__ float Xs[32 * 256];
    const int tid = threadIdx.x;
    const int r   = blockIdx.x;              // residue 0..31
    const int b   = blockIdx.y;
    const int L   = (Tin - r + 31) >> 5;     // subsequence length

    const float* xs = Xsub + ((size_t)(b * 32) * 32 + r) * 256;
    for (int idx = tid; idx < 32 * 256; idx += 256) {
        int ch = idx >> 8, i = idx & 255;
        if (i < L) Xs[ch * 256 + i] = xs[(size_t)ch * (32 * 256) + i];
    }
    __syncthreads();

    int w = L;
    for (int s = 0; s < 5; ++s) {
        const int dd = 1 << s;               // sub-dilation
        const int nw = w - dd;
        const float* wf = wl5 + s * 5120;
        const bool ho = (last != 0) && (s == 4);

        float out0[32];
        const bool a0 = (tid < nw);
        if (a0) layer_slot<256>(Xs, tid, dd, wf, wf + 2048, wf + 4096, out0, ho);
        __syncthreads();
        if (a0) {
#pragma unroll
            for (int oc = 0; oc < 32; ++oc) Xs[oc * 256 + tid] = out0[oc];
        }
        __syncthreads();
        w = nw;
    }

    // store back to normal layout, t = 32*p + r  (final width = L - 31)
    if (tid < w) {
        const int t = (tid << 5) + r;
        float* xp = X + (size_t)b * (RCH * TS) + t;
#pragma unroll
        for (int oc = 0; oc < 32; ++oc) xp[(size_t)oc * TS] = Xs[oc * 256 + tid];
    }
}

// ---------------------------------------------------------------------------
// skip conv + relu, 32 outputs/thread
__global__ __launch_bounds__(256) void skip_kernel(const float* __restrict__ xin,
                                                   const float* __restrict__ sk,
                                                   float* __restrict__ h1) {
    int t = blockIdx.x * 256 + threadIdx.x;
    int sg = blockIdx.y;                     // 8 groups of 32
    int b = blockIdx.z;
    const float* xi = xin + (size_t)(b * RCH) * TS + t;
    const float* wb = sk + sg * 32;
    float acc[32];
#pragma unroll
    for (int j = 0; j < 32; j++) acc[j] = 0.f;
#pragma unroll 4
    for (int dc = 0; dc < 32; dc++) {
        float xv = xi[dc * TS];
        const float* w = wb + dc * 256;
#pragma unroll
        for (int j = 0; j < 32; j++) acc[j] = fmaf(w[j], xv, acc[j]);
    }
    float* ho = h1 + ((size_t)(b * 256) + sg * 32) * TOUT + t;
#pragma unroll
    for (int j = 0; j < 32; j++) ho[j * TOUT] = fmaxf(acc[j], 0.f);
}

// end1 + bias + relu, 32 outputs/thread
__global__ __launch_bounds__(256) void end1_kernel(const float* __restrict__ h1,
                                                   const float* __restrict__ e1t,
                                                   const float* __restrict__ b1,
                                                   float* __restrict__ e1) {
    int t = blockIdx.x * 256 + threadIdx.x;
    int eg = blockIdx.y;                     // 8 groups of 32
    int b = blockIdx.z;
    const float* hp = h1 + (size_t)(b * 256) * TOUT + t;
    const float* wb = e1t + eg * 32;
    float acc[32];
#pragma unroll
    for (int j = 0; j < 32; j++) acc[j] = b1[eg * 32 + j];
#pragma unroll 4
    for (int sc = 0; sc < 256; sc++) {
        float xv = hp[sc * TOUT];
        const float* w = wb + sc * 256;
#pragma unroll
        for (int j = 0; j < 32; j++) acc[j] = fmaf(w[j], xv, acc[j]);
    }
    float* ep = e1 + ((size_t)(b * 256) + eg * 32) * TOUT + t;
#pragma unroll
    for (int j = 0; j < 32; j++) ep[j * TOUT] = fmaxf(acc[j], 0.f);
}

// end2 + bias, transposed store, 32 outputs/thread
__global__ __launch_bounds__(256) void end2_kernel(const float* __restrict__ e1,
                                                   const float* __restrict__ e2t,
                                                   const float* __restrict__ b2,
                                                   float* __restrict__ out) {
    int t = blockIdx.x * 256 + threadIdx.x;
    int cg = blockIdx.y;                     // 8 groups of 32
    int b = blockIdx.z;
    const float* ep = e1 + (size_t)(b * 256) * TOUT + t;
    const float* wb = e2t + cg * 32;
    float acc[32];
#pragma unroll
    for (int j = 0; j < 32; j++) acc[j] = b2[cg * 32 + j];
#pragma unroll 4
    for (int ec = 0; ec < 256; ec++) {
        float xv = ep[ec * TOUT];
        const float* w = wb + ec * 256;
#pragma unroll
        for (int j = 0; j < 32; j++) acc[j] = fmaf(w[j], xv, acc[j]);
    }
    float* op = out + ((size_t)(b * TOUT + t)) * CLS + cg * 32;
#pragma unroll
    for (int j = 0; j < 8; j++)
        ((float4*)op)[j] = make_float4(acc[4*j], acc[4*j+1], acc[4*j+2], acc[4*j+3]);
}

// ---------------------------------------------------------------------------
extern "C" void kernel_launch(void* const* d_in, const int* in_sizes, int n_in,
                              void* d_out, int out_size, void* d_ws, size_t ws_size,
                              hipStream_t stream) {
    const float* x_input    = (const float*)d_in[0];
    const float* start_w    = (const float*)d_in[1];
    const float* filter_w   = (const float*)d_in[2];
    const float* gate_w     = (const float*)d_in[3];
    const float* residual_w = (const float*)d_in[4];
    const float* skip_w     = (const float*)d_in[5];
    const float* end1_w     = (const float*)d_in[6];
    const float* end1_b     = (const float*)d_in[7];
    const float* end2_w     = (const float*)d_in[8];
    const float* end2_b     = (const float*)d_in[9];
    float* ws  = (float*)d_ws;
    float* out = (float*)d_out;

    repack_kernel<<<dim3((352256 + 255) / 256), 256, 0, stream>>>(
        start_w, filter_w, gate_w, residual_w, skip_w, end1_w, end2_w, ws);

    start_kernel<<<dim3(32, 2, NB), 256, 0, stream>>>(
        x_input, ws + OFF_ST, ws + OFF_XA);

    float* xa   = ws + OFF_XA;
    float* xsub = ws + OFF_XSUB;
    int Tin = T0;                            // 8188
    for (int sb = 0; sb < 4; ++sb) {
        const float* wb = ws + OFF_WBLOB + (size_t)sb * 51200;
        int Th = Tin - 31;
        head_kernel<<<dim3((Th + 255) / 256, NB), 256, 0, stream>>>(xa, xsub, wb, Tin);
        tail_kernel<<<dim3(32, NB), 256, 0, stream>>>(xsub, xa, wb + 25600, Th, (sb == 3) ? 1 : 0);
        Tin = Th - 992;
    }
    // Tin == 4096; layer-39 h in xa

    skip_kernel<<<dim3(16, 8, NB), 256, 0, stream>>>(xa, ws + OFF_SK, ws + OFF_H1);
    end1_kernel<<<dim3(16, 8, NB), 256, 0, stream>>>(ws + OFF_H1, ws + OFF_E1T, end1_b, ws + OFF_E1);
    end2_kernel<<<dim3(16, 8, NB), 256, 0, stream>>>(ws + OFF_E1, ws + OFF_E2T, end2_b, out);
}

// Round 3
// 1170.934 us; speedup vs baseline: 5.6689x; 1.7705x over previous
//
#include <hip/hip_runtime.h>
#include <math.h>

// ---------------------------------------------------------------------------
// WaveNet inference, fp32, right-aligned suffix computation.
// Round 6: occupancy fix for the fused 5-layer kernels. Round-5 counters:
// head 274us, VALUBusy 25%, Occupancy 11% -> 1 wave/SIMD (grid 256 blocks),
// pure latency stall. Now 4 threads/timestep (8 oc each), block (64,4) owns
// 64 outputs + 31 halo; h via LDS exchange (2 barriers/layer, double-buffered
// X tile); extras (halo positions 64..93) done by lanes tx<E as second slot.
// Grid 4x bigger -> 4 blocks/CU (LDS 36KB) x 4 waves = 4 waves/SIMD.
// ty == wave == oc-group -> weights stay wave-uniform (s_load).
// head/tail unified (same 8192-float channel stride in both layouts).
// FP accumulation order identical to round-5 -> absmax unchanged.
// Chain: 8188 -h-> 8157 -t-> 7165 -h-> 7134 -t-> 6142 -h-> 6111 -t-> 5119
//        -h-> 5088 -t-> 4096.  Layer 39 (last tail, s=4) emits h only.
// ---------------------------------------------------------------------------

#define TS   8192
#define T0   8188
#define NB   8
#define RCH  32
#define CLS  256
#define TOUT 4096

// workspace layout (float offsets)
#define OFF_WBLOB 0                      // 40 * 5120  (wf[ic][k][oc], wg, wr[ic][oc])
#define OFF_ST    204800                 // start_w^T  [ic][oc]
#define OFF_SK    212992                 // skip_w[39]^T [dc][sc]
#define OFF_E1T   221184                 // end1^T [sc][ec]
#define OFF_E2T   286720                 // end2^T [ec][cc]
#define OFF_XA    352256                 // NB*RCH*TS   (normal layout)
#define OFF_XSUB  (OFF_XA + NB*RCH*TS)   // NB*32*32*256 (sub layout)
#define OFF_H1    (OFF_XSUB + NB*RCH*TS) // NB*256*TOUT
#define OFF_E1    (OFF_H1 + NB*256*TOUT)

__device__ __forceinline__ float tanh_fast(float x) {
    float e = __expf(2.0f * x);
    return 1.0f - 2.0f / (e + 1.0f);
}
__device__ __forceinline__ float sigmoid_fast(float x) {
    return 1.0f / (1.0f + __expf(-x));
}

// ---------------------------------------------------------------------------
__global__ void repack_kernel(const float* __restrict__ start_w,
                              const float* __restrict__ filter_w,
                              const float* __restrict__ gate_w,
                              const float* __restrict__ residual_w,
                              const float* __restrict__ skip_w,
                              const float* __restrict__ end1_w,
                              const float* __restrict__ end2_w,
                              float* __restrict__ ws) {
    int id = blockIdx.x * 256 + threadIdx.x;
    if (id < 204800) {
        int l = id / 5120, r = id % 5120;
        float v;
        if (r < 4096) {                      // wf then wg: [ic][k][oc]
            const float* src = (r < 2048) ? filter_w : gate_w;
            int rr = r & 2047;
            int ic = rr >> 6, k = (rr >> 5) & 1, oc = rr & 31;
            v = src[((l * 32 + oc) * 32 + ic) * 2 + k];
        } else {                             // wr: [ic][oc]
            int rr = r - 4096;
            int ic = rr >> 5, oc = rr & 31;
            v = residual_w[(l * 32 + oc) * 32 + ic];
        }
        ws[OFF_WBLOB + id] = v;
    } else if (id < 204800 + 8192) {
        int r = id - 204800;
        int ic = r >> 5, oc = r & 31;
        ws[OFF_ST + r] = start_w[oc * 256 + ic];
    } else if (id < 212992 + 8192) {
        int r = id - 212992;
        int dc = r >> 8, sc = r & 255;
        ws[OFF_SK + r] = skip_w[(39 * 256 + sc) * 32 + dc];
    } else if (id < 221184 + 65536) {
        int r = id - 221184;
        int sc = r >> 8, ec = r & 255;
        ws[OFF_E1T + r] = end1_w[ec * 256 + sc];
    } else if (id < 286720 + 65536) {
        int r = id - 286720;
        int ec = r >> 8, cc = r & 255;
        ws[OFF_E2T + r] = end2_w[cc * 256 + ec];
    }
}

// ---------------------------------------------------------------------------
// start conv, 16 outputs/thread
__global__ __launch_bounds__(256) void start_kernel(const float* __restrict__ xin,
                                                    const float* __restrict__ st,
                                                    float* __restrict__ xout) {
    int t = blockIdx.x * 256 + threadIdx.x;
    int og = blockIdx.y;                     // 0..1 (16 oc each)
    int b = blockIdx.z;
    if (t >= T0) return;
    const float* xi = xin + (size_t)b * 256 * 16384 + (16384 - T0) + t;
    const float* wb = st + og * 16;
    float acc[16];
#pragma unroll
    for (int c = 0; c < 16; c++) acc[c] = 0.f;
#pragma unroll 4
    for (int ic = 0; ic < 256; ic++) {
        float xv = xi[ic * 16384];
        const float* w = wb + ic * 32;
#pragma unroll
        for (int c = 0; c < 16; c++) acc[c] = fmaf(w[c], xv, acc[c]);
    }
    float* xo = xout + ((size_t)(b * RCH) + og * 16) * TS + t;
#pragma unroll
    for (int c = 0; c < 16; c++) xo[c * TS] = acc[c];
}

// ---------------------------------------------------------------------------
// f/g conv + activation for 8 oc at LDS position p. Weights wave-uniform.
// FP order matches previous rounds (a-tap then c-tap per ic, ic ascending).
__device__ __forceinline__ void fg8(const float* __restrict__ Xc, int p, int d,
                                    const float* __restrict__ wf,
                                    const float* __restrict__ wg,
                                    float h[8]) {
    float f[8], g[8];
#pragma unroll
    for (int j = 0; j < 8; ++j) { f[j] = 0.f; g[j] = 0.f; }
#pragma unroll 4
    for (int ic = 0; ic < 32; ++ic) {
        const float a = Xc[ic * 96 + p];
        const float c = Xc[ic * 96 + p + d];
        const float* w0 = wf + ic * 64;
        const float* w1 = wg + ic * 64;
#pragma unroll
        for (int j = 0; j < 8; ++j) {
            f[j] = fmaf(w0[j],      a, f[j]);
            f[j] = fmaf(w0[32 + j], c, f[j]);
            g[j] = fmaf(w1[j],      a, g[j]);
            g[j] = fmaf(w1[32 + j], c, g[j]);
        }
    }
#pragma unroll
    for (int j = 0; j < 8; ++j) h[j] = tanh_fast(f[j]) * sigmoid_fast(g[j]);
}

// residual 1x1 conv for 8 oc (oc0..oc0+7) at position p: r = X[p+d] + Wr·h
__device__ __forceinline__ void res8(const float* __restrict__ Xc,
                                     const float* __restrict__ Hc,
                                     int p, int d, int oc0,
                                     const float* __restrict__ wrs,  // wr + oc0
                                     float r[8]) {
#pragma unroll
    for (int j = 0; j < 8; ++j) r[j] = Xc[(oc0 + j) * 96 + p + d];
#pragma unroll 4
    for (int ic = 0; ic < 32; ++ic) {
        const float hv = Hc[ic * 96 + p];
        const float* w = wrs + ic * 32;
#pragma unroll
        for (int j = 0; j < 8; ++j) r[j] = fmaf(w[j], hv, r[j]);
    }
}

// ---------------------------------------------------------------------------
// 5 fused layers (dil 1,2,4,8,16). Block (64,4): 64 output positions, wave =
// oc-group of 8. MODE 0: head (X normal -> Xsub). MODE 1: tail (Xsub -> X).
// MODE 2: tail-last (Xsub -> X, layer s=4 emits h only).
// In both layouts the channel stride is 8192 floats -> unified addressing.
template<int MODE>
__global__ __launch_bounds__(256, 4) void five_kernel(const float* __restrict__ in,
                                                      float* __restrict__ outp,
                                                      const float* __restrict__ wl,
                                                      int Tin) {
    __shared__ float Xs[2][32 * 96];
    __shared__ float Hs[32 * 96];
    const int tx = threadIdx.x;
    const int cg = __builtin_amdgcn_readfirstlane(threadIdx.y);
    const int c0 = blockIdx.x * 64;
    const int b  = (MODE == 0) ? blockIdx.y : blockIdx.z;
    const int r  = (MODE == 0) ? 0 : blockIdx.y;
    const int L  = (MODE == 0) ? Tin : ((Tin - r + 31) >> 5);
    const int Lw = min(95, L - c0);

    // load: coalesced rows; head stride-1 in t, tail stride-1 in subseq index
    const float* src = in + (size_t)b * 262144 + (size_t)r * 256 + c0;
    for (int ch = cg; ch < 32; ch += 4)
        for (int p = tx; p < Lw; p += 64)
            Xs[0][ch * 96 + p] = src[(size_t)ch * 8192 + p];
    __syncthreads();

    int cb = 0, w = Lw;
#pragma unroll
    for (int s = 0; s < 5; ++s) {
        const int d  = 1 << s;
        const int nw = w - d;
        const int E  = nw - 64;                    // extra halo positions
        const float* wf  = wl + s * 5120 + cg * 8;
        const float* wg  = wf + 2048;
        const float* wrs = wl + s * 5120 + 4096 + cg * 8;
        const float* Xc  = Xs[cb];
        const bool a0 = (tx < nw);
        const bool a1 = (tx < E);

        float h0[8], h1[8];
        if (a0) fg8(Xc, tx, d, wf, wg, h0);
        if (a1) fg8(Xc, 64 + tx, d, wf, wg, h1);

        if (MODE == 2 && s == 4) {                 // layer 39: h only, reg-direct store
            if (a0) {
                const int t = ((c0 + tx) << 5) + r;
                float* dst = outp + (size_t)b * 262144 + t;
#pragma unroll
                for (int j = 0; j < 8; ++j)
                    dst[(size_t)(cg * 8 + j) * 8192] = h0[j];
            }
            return;
        }

        if (a0) {
#pragma unroll
            for (int j = 0; j < 8; ++j) Hs[(cg * 8 + j) * 96 + tx] = h0[j];
        }
        if (a1) {
#pragma unroll
            for (int j = 0; j < 8; ++j) Hs[(cg * 8 + j) * 96 + 64 + tx] = h1[j];
        }
        __syncthreads();

        float r0[8], r1[8];
        if (a0) res8(Xc, Hs, tx, d, cg * 8, wrs, r0);
        if (a1) res8(Xc, Hs, 64 + tx, d, cg * 8, wrs, r1);

        if (s == 4) {                              // final: reg-direct store (E==0 here)
            if (a0) {
                if (MODE == 0) {                   // -> Xsub[b][oc][t&31][t>>5]
                    const int t = c0 + tx;
                    float* dst = outp + (size_t)b * 262144 + (size_t)(t & 31) * 256 + (t >> 5);
#pragma unroll
                    for (int j = 0; j < 8; ++j)
                        dst[(size_t)(cg * 8 + j) * 8192] = r0[j];
                } else {                           // -> X[b][oc][32*p + r]
                    const int t = ((c0 + tx) << 5) + r;
                    float* dst = outp + (size_t)b * 262144 + t;
#pragma unroll
                    for (int j = 0; j < 8; ++j)
                        dst[(size_t)(cg * 8 + j) * 8192] = r0[j];
                }
            }
        } else {
            float* Xn = Xs[cb ^ 1];
            if (a0) {
#pragma unroll
                for (int j = 0; j < 8; ++j) Xn[(cg * 8 + j) * 96 + tx] = r0[j];
            }
            if (a1) {
#pragma unroll
                for (int j = 0; j < 8; ++j) Xn[(cg * 8 + j) * 96 + 64 + tx] = r1[j];
            }
            __syncthreads();
            cb ^= 1;
        }
        w = nw;
    }
}

// ---------------------------------------------------------------------------
// skip conv + relu, 32 outputs/thread
__global__ __launch_bounds__(256) void skip_kernel(const float* __restrict__ xin,
                                                   const float* __restrict__ sk,
                                                   float* __restrict__ h1) {
    int t = blockIdx.x * 256 + threadIdx.x;
    int sg = blockIdx.y;                     // 8 groups of 32
    int b = blockIdx.z;
    const float* xi = xin + (size_t)(b * RCH) * TS + t;
    const float* wb = sk + sg * 32;
    float acc[32];
#pragma unroll
    for (int j = 0; j < 32; j++) acc[j] = 0.f;
#pragma unroll 4
    for (int dc = 0; dc < 32; dc++) {
        float xv = xi[dc * TS];
        const float* w = wb + dc * 256;
#pragma unroll
        for (int j = 0; j < 32; j++) acc[j] = fmaf(w[j], xv, acc[j]);
    }
    float* ho = h1 + ((size_t)(b * 256) + sg * 32) * TOUT + t;
#pragma unroll
    for (int j = 0; j < 32; j++) ho[j * TOUT] = fmaxf(acc[j], 0.f);
}

// end1 + bias + relu, 32 outputs/thread
__global__ __launch_bounds__(256) void end1_kernel(const float* __restrict__ h1,
                                                   const float* __restrict__ e1t,
                                                   const float* __restrict__ b1,
                                                   float* __restrict__ e1) {
    int t = blockIdx.x * 256 + threadIdx.x;
    int eg = blockIdx.y;                     // 8 groups of 32
    int b = blockIdx.z;
    const float* hp = h1 + (size_t)(b * 256) * TOUT + t;
    const float* wb = e1t + eg * 32;
    float acc[32];
#pragma unroll
    for (int j = 0; j < 32; j++) acc[j] = b1[eg * 32 + j];
#pragma unroll 4
    for (int sc = 0; sc < 256; sc++) {
        float xv = hp[sc * TOUT];
        const float* w = wb + sc * 256;
#pragma unroll
        for (int j = 0; j < 32; j++) acc[j] = fmaf(w[j], xv, acc[j]);
    }
    float* ep = e1 + ((size_t)(b * 256) + eg * 32) * TOUT + t;
#pragma unroll
    for (int j = 0; j < 32; j++) ep[j * TOUT] = fmaxf(acc[j], 0.f);
}

// end2 + bias, transposed store, 32 outputs/thread
__global__ __launch_bounds__(256) void end2_kernel(const float* __restrict__ e1,
                                                   const float* __restrict__ e2t,
                                                   const float* __restrict__ b2,
                                                   float* __restrict__ out) {
    int t = blockIdx.x * 256 + threadIdx.x;
    int cg = blockIdx.y;                     // 8 groups of 32
    int b = blockIdx.z;
    const float* ep = e1 + (size_t)(b * 256) * TOUT + t;
    const float* wb = e2t + cg * 32;
    float acc[32];
#pragma unroll
    for (int j = 0; j < 32; j++) acc[j] = b2[cg * 32 + j];
#pragma unroll 4
    for (int ec = 0; ec < 256; ec++) {
        float xv = ep[ec * TOUT];
        const float* w = wb + ec * 256;
#pragma unroll
        for (int j = 0; j < 32; j++) acc[j] = fmaf(w[j], xv, acc[j]);
    }
    float* op = out + ((size_t)(b * TOUT + t)) * CLS + cg * 32;
#pragma unroll
    for (int j = 0; j < 8; j++)
        ((float4*)op)[j] = make_float4(acc[4*j], acc[4*j+1], acc[4*j+2], acc[4*j+3]);
}

// ---------------------------------------------------------------------------
extern "C" void kernel_launch(void* const* d_in, const int* in_sizes, int n_in,
                              void* d_out, int out_size, void* d_ws, size_t ws_size,
                              hipStream_t stream) {
    const float* x_input    = (const float*)d_in[0];
    const float* start_w    = (const float*)d_in[1];
    const float* filter_w   = (const float*)d_in[2];
    const float* gate_w     = (const float*)d_in[3];
    const float* residual_w = (const float*)d_in[4];
    const float* skip_w     = (const float*)d_in[5];
    const float* end1_w     = (const float*)d_in[6];
    const float* end1_b     = (const float*)d_in[7];
    const float* end2_w     = (const float*)d_in[8];
    const float* end2_b     = (const float*)d_in[9];
    float* ws  = (float*)d_ws;
    float* out = (float*)d_out;

    repack_kernel<<<dim3((352256 + 255) / 256), 256, 0, stream>>>(
        start_w, filter_w, gate_w, residual_w, skip_w, end1_w, end2_w, ws);

    start_kernel<<<dim3(32, 2, NB), 256, 0, stream>>>(
        x_input, ws + OFF_ST, ws + OFF_XA);

    float* xa   = ws + OFF_XA;
    float* xsub = ws + OFF_XSUB;
    int Tin = T0;                            // 8188
    for (int sb = 0; sb < 4; ++sb) {
        const float* wb = ws + OFF_WBLOB + (size_t)sb * 51200;
        const int Th   = Tin - 31;           // head output length
        const int nbh  = (Th + 63) / 64;
        five_kernel<0><<<dim3(nbh, NB), dim3(64, 4), 0, stream>>>(xa, xsub, wb, Tin);

        const int Lmax  = (Th + 31) >> 5;    // longest residue subsequence
        const int LoutM = Lmax - 31;
        const int nbt   = (LoutM + 63) / 64;
        if (sb < 3)
            five_kernel<1><<<dim3(nbt, 32, NB), dim3(64, 4), 0, stream>>>(xsub, xa, wb + 25600, Th);
        else
            five_kernel<2><<<dim3(nbt, 32, NB), dim3(64, 4), 0, stream>>>(xsub, xa, wb + 25600, Th);
        Tin = Th - 992;
    }
    // Tin == 4096; layer-39 h in xa

    skip_kernel<<<dim3(16, 8, NB), 256, 0, stream>>>(xa, ws + OFF_SK, ws + OFF_H1);
    end1_kernel<<<dim3(16, 8, NB), 256, 0, stream>>>(ws + OFF_H1, ws + OFF_E1T, end1_b, ws + OFF_E1);
    end2_kernel<<<dim3(16, 8, NB), 256, 0, stream>>>(ws + OFF_E1, ws + OFF_E2T, end2_b, out);
}

// Round 4
// 890.432 us; speedup vs baseline: 7.4547x; 1.3150x over previous
//
#include <hip/hip_runtime.h>
#include <math.h>

// ---------------------------------------------------------------------------
// WaveNet inference, fp32, right-aligned suffix computation.
// Round 7: five_kernel issue/stall fix. Round-6 counters: 122us/dispatch,
// VALUBusy 43-50%, Occ 30% -> ~60% stall (s_load/ds_read lgkmcnt mixing at
// 4 waves/SIMD) + 1.8x halo issue multiplier (predicated extra fg8 slot).
// Now: W=96 outputs/block (tile 127, exactly 2 slots/thread, no extras);
// merged ic-loop computes both slots sharing each weight fetch; block (64,8)
// wave=4oc -> 8 waves/block; single-X in-place LDS (X reads all pre-barrier,
// writes post-barrier; __syncthreads' lgkmcnt(0) drain makes preloaded taps
// safe) -> LDS 32KB. Occupancy ~21 waves/CU vs ~10.
// FP order per output identical to rounds 5/6 -> absmax must stay 2.4e-4.
// Chain: 8188 -h-> 8157 -t-> 7165 -h-> 7134 -t-> 6142 -h-> 6111 -t-> 5119
//        -h-> 5088 -t-> 4096.  Layer 39 (last tail, s=4) emits h only.
// ---------------------------------------------------------------------------

#define TS   8192
#define T0   8188
#define NB   8
#define RCH  32
#define CLS  256
#define TOUT 4096

// workspace layout (float offsets)
#define OFF_WBLOB 0                      // 40 * 5120  (wf[ic][k][oc], wg, wr[ic][oc])
#define OFF_ST    204800                 // start_w^T  [ic][oc]
#define OFF_SK    212992                 // skip_w[39]^T [dc][sc]
#define OFF_E1T   221184                 // end1^T [sc][ec]
#define OFF_E2T   286720                 // end2^T [ec][cc]
#define OFF_XA    352256                 // NB*RCH*TS   (normal layout)
#define OFF_XSUB  (OFF_XA + NB*RCH*TS)   // NB*32*32*256 (sub layout)
#define OFF_H1    (OFF_XSUB + NB*RCH*TS) // NB*256*TOUT
#define OFF_E1    (OFF_H1 + NB*256*TOUT)

__device__ __forceinline__ float tanh_fast(float x) {
    float e = __expf(2.0f * x);
    return 1.0f - 2.0f / (e + 1.0f);
}
__device__ __forceinline__ float sigmoid_fast(float x) {
    return 1.0f / (1.0f + __expf(-x));
}

// ---------------------------------------------------------------------------
__global__ void repack_kernel(const float* __restrict__ start_w,
                              const float* __restrict__ filter_w,
                              const float* __restrict__ gate_w,
                              const float* __restrict__ residual_w,
                              const float* __restrict__ skip_w,
                              const float* __restrict__ end1_w,
                              const float* __restrict__ end2_w,
                              float* __restrict__ ws) {
    int id = blockIdx.x * 256 + threadIdx.x;
    if (id < 204800) {
        int l = id / 5120, r = id % 5120;
        float v;
        if (r < 4096) {                      // wf then wg: [ic][k][oc]
            const float* src = (r < 2048) ? filter_w : gate_w;
            int rr = r & 2047;
            int ic = rr >> 6, k = (rr >> 5) & 1, oc = rr & 31;
            v = src[((l * 32 + oc) * 32 + ic) * 2 + k];
        } else {                             // wr: [ic][oc]
            int rr = r - 4096;
            int ic = rr >> 5, oc = rr & 31;
            v = residual_w[(l * 32 + oc) * 32 + ic];
        }
        ws[OFF_WBLOB + id] = v;
    } else if (id < 204800 + 8192) {
        int r = id - 204800;
        int ic = r >> 5, oc = r & 31;
        ws[OFF_ST + r] = start_w[oc * 256 + ic];
    } else if (id < 212992 + 8192) {
        int r = id - 212992;
        int dc = r >> 8, sc = r & 255;
        ws[OFF_SK + r] = skip_w[(39 * 256 + sc) * 32 + dc];
    } else if (id < 221184 + 65536) {
        int r = id - 221184;
        int sc = r >> 8, ec = r & 255;
        ws[OFF_E1T + r] = end1_w[ec * 256 + sc];
    } else if (id < 286720 + 65536) {
        int r = id - 286720;
        int ec = r >> 8, cc = r & 255;
        ws[OFF_E2T + r] = end2_w[cc * 256 + ec];
    }
}

// ---------------------------------------------------------------------------
// start conv, 16 outputs/thread
__global__ __launch_bounds__(256) void start_kernel(const float* __restrict__ xin,
                                                    const float* __restrict__ st,
                                                    float* __restrict__ xout) {
    int t = blockIdx.x * 256 + threadIdx.x;
    int og = blockIdx.y;                     // 0..1 (16 oc each)
    int b = blockIdx.z;
    if (t >= T0) return;
    const float* xi = xin + (size_t)b * 256 * 16384 + (16384 - T0) + t;
    const float* wb = st + og * 16;
    float acc[16];
#pragma unroll
    for (int c = 0; c < 16; c++) acc[c] = 0.f;
#pragma unroll 4
    for (int ic = 0; ic < 256; ic++) {
        float xv = xi[ic * 16384];
        const float* w = wb + ic * 32;
#pragma unroll
        for (int c = 0; c < 16; c++) acc[c] = fmaf(w[c], xv, acc[c]);
    }
    float* xo = xout + ((size_t)(b * RCH) + og * 16) * TS + t;
#pragma unroll
    for (int c = 0; c < 16; c++) xo[c * TS] = acc[c];
}

// ---------------------------------------------------------------------------
// 5 fused layers (dil 1,2,4,8,16). Block (64,8): wave = 4-oc group, 96 output
// positions per block (tile 127, slots p0=tx, p1=64+tx). Single in-place X
// buffer: all X reads (fg taps + residual taps) issued pre-barrier; X writes
// post-barrier. MODE 0: head (X normal -> Xsub). MODE 1: tail (Xsub -> X).
// MODE 2: tail-last (Xsub -> X, layer s=4 emits h only).
template<int MODE>
__global__ __launch_bounds__(512, 4) void five_kernel(const float* __restrict__ in,
                                                      float* __restrict__ outp,
                                                      const float* __restrict__ wl,
                                                      int Tin) {
    __shared__ float Xs[32 * 128];
    __shared__ float Hs[32 * 128];
    const int tx  = threadIdx.x;
    const int cg  = __builtin_amdgcn_readfirstlane(threadIdx.y);   // 0..7
    const int oc0 = cg * 4;
    const int c0  = blockIdx.x * 96;
    const int b   = (MODE == 0) ? blockIdx.y : blockIdx.z;
    const int r   = (MODE == 0) ? 0 : blockIdx.y;
    const int L   = (MODE == 0) ? Tin : ((Tin - r + 31) >> 5);
    const int Lw  = min(127, L - c0);

    // coalesced tile load (head: stride-1 in t; tail: stride-1 in subseq idx)
    const float* src = in + (size_t)b * 262144 + (size_t)r * 256 + c0;
    for (int ch = cg; ch < 32; ch += 8)
        for (int p = tx; p < Lw; p += 64)
            Xs[ch * 128 + p] = src[(size_t)ch * 8192 + p];
    __syncthreads();

    int w = Lw;
#pragma unroll
    for (int s = 0; s < 5; ++s) {
        const int d  = 1 << s;
        const int nw = w - d;
        const bool a0 = (tx < nw);
        const bool a1 = (64 + tx < nw);
        const int p0 = a0 ? tx : 0;            // clamped: in-bounds garbage
        const int p1 = a1 ? (64 + tx) : 0;
        const float* wf = wl + s * 5120 + oc0; // wf[ic*64 + k*32 + oc]
        const float* wg = wf + 2048;
        const float* wr = wl + s * 5120 + 4096 + oc0;

        // residual taps X[p+d], preloaded (X overwritten post-barrier)
        float t0[4], t1[4];
#pragma unroll
        for (int j = 0; j < 4; ++j) {
            t0[j] = Xs[(oc0 + j) * 128 + p0 + d];
            t1[j] = Xs[(oc0 + j) * 128 + p1 + d];
        }

        float f0[4], g0[4], f1[4], g1[4];
#pragma unroll
        for (int j = 0; j < 4; ++j) { f0[j]=0.f; g0[j]=0.f; f1[j]=0.f; g1[j]=0.f; }
#pragma unroll 4
        for (int ic = 0; ic < 32; ++ic) {
            const float a0v = Xs[ic * 128 + p0];
            const float c0v = Xs[ic * 128 + p0 + d];
            const float a1v = Xs[ic * 128 + p1];
            const float c1v = Xs[ic * 128 + p1 + d];
            const float* w0 = wf + ic * 64;
            const float* w1 = wg + ic * 64;
#pragma unroll
            for (int j = 0; j < 4; ++j) {        // per-acc order: a then c, ic asc
                f0[j] = fmaf(w0[j],      a0v, f0[j]);
                f0[j] = fmaf(w0[32 + j], c0v, f0[j]);
                g0[j] = fmaf(w1[j],      a0v, g0[j]);
                g0[j] = fmaf(w1[32 + j], c0v, g0[j]);
                f1[j] = fmaf(w0[j],      a1v, f1[j]);
                f1[j] = fmaf(w0[32 + j], c1v, f1[j]);
                g1[j] = fmaf(w1[j],      a1v, g1[j]);
                g1[j] = fmaf(w1[32 + j], c1v, g1[j]);
            }
        }
        float h0[4], h1[4];
#pragma unroll
        for (int j = 0; j < 4; ++j) {
            h0[j] = tanh_fast(f0[j]) * sigmoid_fast(g0[j]);
            h1[j] = tanh_fast(f1[j]) * sigmoid_fast(g1[j]);
        }

        if (MODE == 2 && s == 4) {               // layer 39: h only, reg-direct
            if (a0) {
                float* dst = outp + (size_t)b * 262144 + (size_t)(((c0 + tx) << 5) + r);
#pragma unroll
                for (int j = 0; j < 4; ++j) dst[(size_t)(oc0 + j) * 8192] = h0[j];
            }
            if (a1) {
                float* dst = outp + (size_t)b * 262144 + (size_t)(((c0 + 64 + tx) << 5) + r);
#pragma unroll
                for (int j = 0; j < 4; ++j) dst[(size_t)(oc0 + j) * 8192] = h1[j];
            }
            return;
        }

        if (a0) {
#pragma unroll
            for (int j = 0; j < 4; ++j) Hs[(oc0 + j) * 128 + tx] = h0[j];
        }
        if (a1) {
#pragma unroll
            for (int j = 0; j < 4; ++j) Hs[(oc0 + j) * 128 + 64 + tx] = h1[j];
        }
        __syncthreads();   // X reads + H writes complete (per-thread lgkmcnt(0))

        float r0[4], r1[4];
#pragma unroll
        for (int j = 0; j < 4; ++j) { r0[j] = t0[j]; r1[j] = t1[j]; }
#pragma unroll 4
        for (int ic = 0; ic < 32; ++ic) {
            const float h0v = Hs[ic * 128 + p0];
            const float h1v = Hs[ic * 128 + p1];
            const float* wv = wr + ic * 32;
#pragma unroll
            for (int j = 0; j < 4; ++j) {
                r0[j] = fmaf(wv[j], h0v, r0[j]);
                r1[j] = fmaf(wv[j], h1v, r1[j]);
            }
        }

        if (s == 4) {                            // final: reg-direct global store
            if (MODE == 0) {                     // -> Xsub[b][oc][t&31][t>>5]
                if (a0) {
                    const int t = c0 + tx;
                    float* dst = outp + (size_t)b * 262144 + (size_t)(t & 31) * 256 + (t >> 5);
#pragma unroll
                    for (int j = 0; j < 4; ++j) dst[(size_t)(oc0 + j) * 8192] = r0[j];
                }
                if (a1) {
                    const int t = c0 + 64 + tx;
                    float* dst = outp + (size_t)b * 262144 + (size_t)(t & 31) * 256 + (t >> 5);
#pragma unroll
                    for (int j = 0; j < 4; ++j) dst[(size_t)(oc0 + j) * 8192] = r1[j];
                }
            } else {                             // -> X[b][oc][32*p + r]
                if (a0) {
                    float* dst = outp + (size_t)b * 262144 + (size_t)(((c0 + tx) << 5) + r);
#pragma unroll
                    for (int j = 0; j < 4; ++j) dst[(size_t)(oc0 + j) * 8192] = r0[j];
                }
                if (a1) {
                    float* dst = outp + (size_t)b * 262144 + (size_t)(((c0 + 64 + tx) << 5) + r);
#pragma unroll
                    for (int j = 0; j < 4; ++j) dst[(size_t)(oc0 + j) * 8192] = r1[j];
                }
            }
        } else {                                 // in-place X update
            if (a0) {
#pragma unroll
                for (int j = 0; j < 4; ++j) Xs[(oc0 + j) * 128 + tx] = r0[j];
            }
            if (a1) {
#pragma unroll
                for (int j = 0; j < 4; ++j) Xs[(oc0 + j) * 128 + 64 + tx] = r1[j];
            }
            __syncthreads();                     // X writes visible for next layer
        }
        w = nw;
    }
}

// ---------------------------------------------------------------------------
// skip conv + relu, 32 outputs/thread
__global__ __launch_bounds__(256) void skip_kernel(const float* __restrict__ xin,
                                                   const float* __restrict__ sk,
                                                   float* __restrict__ h1) {
    int t = blockIdx.x * 256 + threadIdx.x;
    int sg = blockIdx.y;                     // 8 groups of 32
    int b = blockIdx.z;
    const float* xi = xin + (size_t)(b * RCH) * TS + t;
    const float* wb = sk + sg * 32;
    float acc[32];
#pragma unroll
    for (int j = 0; j < 32; j++) acc[j] = 0.f;
#pragma unroll 4
    for (int dc = 0; dc < 32; dc++) {
        float xv = xi[dc * TS];
        const float* w = wb + dc * 256;
#pragma unroll
        for (int j = 0; j < 32; j++) acc[j] = fmaf(w[j], xv, acc[j]);
    }
    float* ho = h1 + ((size_t)(b * 256) + sg * 32) * TOUT + t;
#pragma unroll
    for (int j = 0; j < 32; j++) ho[j * TOUT] = fmaxf(acc[j], 0.f);
}

// end1 + bias + relu, 32 outputs/thread
__global__ __launch_bounds__(256) void end1_kernel(const float* __restrict__ h1,
                                                   const float* __restrict__ e1t,
                                                   const float* __restrict__ b1,
                                                   float* __restrict__ e1) {
    int t = blockIdx.x * 256 + threadIdx.x;
    int eg = blockIdx.y;                     // 8 groups of 32
    int b = blockIdx.z;
    const float* hp = h1 + (size_t)(b * 256) * TOUT + t;
    const float* wb = e1t + eg * 32;
    float acc[32];
#pragma unroll
    for (int j = 0; j < 32; j++) acc[j] = b1[eg * 32 + j];
#pragma unroll 4
    for (int sc = 0; sc < 256; sc++) {
        float xv = hp[sc * TOUT];
        const float* w = wb + sc * 256;
#pragma unroll
        for (int j = 0; j < 32; j++) acc[j] = fmaf(w[j], xv, acc[j]);
    }
    float* ep = e1 + ((size_t)(b * 256) + eg * 32) * TOUT + t;
#pragma unroll
    for (int j = 0; j < 32; j++) ep[j * TOUT] = fmaxf(acc[j], 0.f);
}

// end2 + bias, transposed store, 32 outputs/thread
__global__ __launch_bounds__(256) void end2_kernel(const float* __restrict__ e1,
                                                   const float* __restrict__ e2t,
                                                   const float* __restrict__ b2,
                                                   float* __restrict__ out) {
    int t = blockIdx.x * 256 + threadIdx.x;
    int cg = blockIdx.y;                     // 8 groups of 32
    int b = blockIdx.z;
    const float* ep = e1 + (size_t)(b * 256) * TOUT + t;
    const float* wb = e2t + cg * 32;
    float acc[32];
#pragma unroll
    for (int j = 0; j < 32; j++) acc[j] = b2[cg * 32 + j];
#pragma unroll 4
    for (int ec = 0; ec < 256; ec++) {
        float xv = ep[ec * TOUT];
        const float* w = wb + ec * 256;
#pragma unroll
        for (int j = 0; j < 32; j++) acc[j] = fmaf(w[j], xv, acc[j]);
    }
    float* op = out + ((size_t)(b * TOUT + t)) * CLS + cg * 32;
#pragma unroll
    for (int j = 0; j < 8; j++)
        ((float4*)op)[j] = make_float4(acc[4*j], acc[4*j+1], acc[4*j+2], acc[4*j+3]);
}

// ---------------------------------------------------------------------------
extern "C" void kernel_launch(void* const* d_in, const int* in_sizes, int n_in,
                              void* d_out, int out_size, void* d_ws, size_t ws_size,
                              hipStream_t stream) {
    const float* x_input    = (const float*)d_in[0];
    const float* start_w    = (const float*)d_in[1];
    const float* filter_w   = (const float*)d_in[2];
    const float* gate_w     = (const float*)d_in[3];
    const float* residual_w = (const float*)d_in[4];
    const float* skip_w     = (const float*)d_in[5];
    const float* end1_w     = (const float*)d_in[6];
    const float* end1_b     = (const float*)d_in[7];
    const float* end2_w     = (const float*)d_in[8];
    const float* end2_b     = (const float*)d_in[9];
    float* ws  = (float*)d_ws;
    float* out = (float*)d_out;

    repack_kernel<<<dim3((352256 + 255) / 256), 256, 0, stream>>>(
        start_w, filter_w, gate_w, residual_w, skip_w, end1_w, end2_w, ws);

    start_kernel<<<dim3(32, 2, NB), 256, 0, stream>>>(
        x_input, ws + OFF_ST, ws + OFF_XA);

    float* xa   = ws + OFF_XA;
    float* xsub = ws + OFF_XSUB;
    int Tin = T0;                            // 8188
    for (int sb = 0; sb < 4; ++sb) {
        const float* wb = ws + OFF_WBLOB + (size_t)sb * 51200;
        const int Th  = Tin - 31;            // head output length
        const int nbh = (Th + 95) / 96;
        five_kernel<0><<<dim3(nbh, NB), dim3(64, 8), 0, stream>>>(xa, xsub, wb, Tin);

        const int Lmax  = (Th + 31) >> 5;    // longest residue subsequence
        const int LoutM = Lmax - 31;
        const int nbt   = (LoutM + 95) / 96;
        if (sb < 3)
            five_kernel<1><<<dim3(nbt, 32, NB), dim3(64, 8), 0, stream>>>(xsub, xa, wb + 25600, Th);
        else
            five_kernel<2><<<dim3(nbt, 32, NB), dim3(64, 8), 0, stream>>>(xsub, xa, wb + 25600, Th);
        Tin = Th - 992;
    }
    // Tin == 4096; layer-39 h in xa

    skip_kernel<<<dim3(16, 8, NB), 256, 0, stream>>>(xa, ws + OFF_SK, ws + OFF_H1);
    end1_kernel<<<dim3(16, 8, NB), 256, 0, stream>>>(ws + OFF_H1, ws + OFF_E1T, end1_b, ws + OFF_E1);
    end2_kernel<<<dim3(16, 8, NB), 256, 0, stream>>>(ws + OFF_E1, ws + OFF_E2T, end2_b, out);
}

// Round 5
// 890.340 us; speedup vs baseline: 7.4555x; 1.0001x over previous
//
#include <hip/hip_runtime.h>
#include <math.h>

// ---------------------------------------------------------------------------
// WaveNet inference, fp32, right-aligned suffix computation.
// Round 8: weight fetches moved from s_load (scalar, out-of-order lgkmcnt ->
// forced lgkmcnt(0) drains mixed with ds_read) to global_load_dwordx4 via the
// LDS-zero trick (vz: runtime 0, compiler-opaque -> VGPR addressing). Weight
// latency now on vmcnt (pipelined independently); ds_read waits become
// fine-grained in-order lgkmcnt(N). Round-7 counters: VALUBusy 50%, VGPR 32,
// 97us/dispatch vs 28-32us FMA floor -> latency-stall on weight drains.
// FP order per output identical to rounds 5-7 -> absmax must stay 2.4e-4.
// Chain: 8188 -h-> 8157 -t-> 7165 -h-> 7134 -t-> 6142 -h-> 6111 -t-> 5119
//        -h-> 5088 -t-> 4096.  Layer 39 (last tail, s=4) emits h only.
// ---------------------------------------------------------------------------

#define TS   8192
#define T0   8188
#define NB   8
#define RCH  32
#define CLS  256
#define TOUT 4096

// workspace layout (float offsets)
#define OFF_WBLOB 0                      // 40 * 5120  (wf[ic][k][oc], wg, wr[ic][oc])
#define OFF_ST    204800                 // start_w^T  [ic][oc]
#define OFF_SK    212992                 // skip_w[39]^T [dc][sc]
#define OFF_E1T   221184                 // end1^T [sc][ec]
#define OFF_E2T   286720                 // end2^T [ec][cc]
#define OFF_XA    352256                 // NB*RCH*TS   (normal layout)
#define OFF_XSUB  (OFF_XA + NB*RCH*TS)   // NB*32*32*256 (sub layout)
#define OFF_H1    (OFF_XSUB + NB*RCH*TS) // NB*256*TOUT
#define OFF_E1    (OFF_H1 + NB*256*TOUT)

__device__ __forceinline__ float tanh_fast(float x) {
    float e = __expf(2.0f * x);
    return 1.0f - 2.0f / (e + 1.0f);
}
__device__ __forceinline__ float sigmoid_fast(float x) {
    return 1.0f / (1.0f + __expf(-x));
}

// ---------------------------------------------------------------------------
__global__ void repack_kernel(const float* __restrict__ start_w,
                              const float* __restrict__ filter_w,
                              const float* __restrict__ gate_w,
                              const float* __restrict__ residual_w,
                              const float* __restrict__ skip_w,
                              const float* __restrict__ end1_w,
                              const float* __restrict__ end2_w,
                              float* __restrict__ ws) {
    int id = blockIdx.x * 256 + threadIdx.x;
    if (id < 204800) {
        int l = id / 5120, r = id % 5120;
        float v;
        if (r < 4096) {                      // wf then wg: [ic][k][oc]
            const float* src = (r < 2048) ? filter_w : gate_w;
            int rr = r & 2047;
            int ic = rr >> 6, k = (rr >> 5) & 1, oc = rr & 31;
            v = src[((l * 32 + oc) * 32 + ic) * 2 + k];
        } else {                             // wr: [ic][oc]
            int rr = r - 4096;
            int ic = rr >> 5, oc = rr & 31;
            v = residual_w[(l * 32 + oc) * 32 + ic];
        }
        ws[OFF_WBLOB + id] = v;
    } else if (id < 204800 + 8192) {
        int r = id - 204800;
        int ic = r >> 5, oc = r & 31;
        ws[OFF_ST + r] = start_w[oc * 256 + ic];
    } else if (id < 212992 + 8192) {
        int r = id - 212992;
        int dc = r >> 8, sc = r & 255;
        ws[OFF_SK + r] = skip_w[(39 * 256 + sc) * 32 + dc];
    } else if (id < 221184 + 65536) {
        int r = id - 221184;
        int sc = r >> 8, ec = r & 255;
        ws[OFF_E1T + r] = end1_w[ec * 256 + sc];
    } else if (id < 286720 + 65536) {
        int r = id - 286720;
        int ec = r >> 8, cc = r & 255;
        ws[OFF_E2T + r] = end2_w[cc * 256 + ec];
    }
}

// ---------------------------------------------------------------------------
// start conv, 16 outputs/thread; weights vector-loaded (vz trick)
__global__ __launch_bounds__(256) void start_kernel(const float* __restrict__ xin,
                                                    const float* __restrict__ st,
                                                    float* __restrict__ xout) {
    __shared__ int zs;
    if (threadIdx.x == 0) zs = 0;
    __syncthreads();
    const int vz = zs;                       // runtime 0, compiler-opaque
    int t = blockIdx.x * 256 + threadIdx.x;
    int og = blockIdx.y;                     // 0..1 (16 oc each)
    int b = blockIdx.z;
    if (t >= T0) return;
    const float* xi = xin + (size_t)b * 256 * 16384 + (16384 - T0) + t;
    const float* wb = st + vz + og * 16;
    float acc[16];
#pragma unroll
    for (int c = 0; c < 16; c++) acc[c] = 0.f;
#pragma unroll 4
    for (int ic = 0; ic < 256; ic++) {
        float xv = xi[ic * 16384];
        const float* w = wb + ic * 32;
        const float4 w0 = *(const float4*)(w);
        const float4 w1 = *(const float4*)(w + 4);
        const float4 w2 = *(const float4*)(w + 8);
        const float4 w3 = *(const float4*)(w + 12);
        const float ww[16] = {w0.x,w0.y,w0.z,w0.w, w1.x,w1.y,w1.z,w1.w,
                              w2.x,w2.y,w2.z,w2.w, w3.x,w3.y,w3.z,w3.w};
#pragma unroll
        for (int c = 0; c < 16; c++) acc[c] = fmaf(ww[c], xv, acc[c]);
    }
    float* xo = xout + ((size_t)(b * RCH) + og * 16) * TS + t;
#pragma unroll
    for (int c = 0; c < 16; c++) xo[c * TS] = acc[c];
}

// ---------------------------------------------------------------------------
// 5 fused layers (dil 1,2,4,8,16). Block (64,8): wave = 4-oc group, 96 output
// positions per block (tile 127, slots p0=tx, p1=64+tx). Single in-place X
// buffer: all X reads pre-barrier; X writes post-barrier. Weights via
// global_load_dwordx4 (vz trick). MODE 0: head (X normal -> Xsub).
// MODE 1: tail (Xsub -> X). MODE 2: tail-last (layer s=4 emits h only).
template<int MODE>
__global__ __launch_bounds__(512, 4) void five_kernel(const float* __restrict__ in,
                                                      float* __restrict__ outp,
                                                      const float* __restrict__ wl,
                                                      int Tin) {
    __shared__ float Xs[32 * 128];
    __shared__ float Hs[32 * 128];
    __shared__ int zsh;
    const int tx  = threadIdx.x;
    const int cg  = __builtin_amdgcn_readfirstlane(threadIdx.y);   // 0..7
    const int oc0 = cg * 4;
    const int c0  = blockIdx.x * 96;
    const int b   = (MODE == 0) ? blockIdx.y : blockIdx.z;
    const int r   = (MODE == 0) ? 0 : blockIdx.y;
    const int L   = (MODE == 0) ? Tin : ((Tin - r + 31) >> 5);
    const int Lw  = min(127, L - c0);

    if (tx == 0 && threadIdx.y == 0) zsh = 0;

    // coalesced tile load (head: stride-1 in t; tail: stride-1 in subseq idx)
    const float* src = in + (size_t)b * 262144 + (size_t)r * 256 + c0;
    for (int ch = cg; ch < 32; ch += 8)
        for (int p = tx; p < Lw; p += 64)
            Xs[ch * 128 + p] = src[(size_t)ch * 8192 + p];
    __syncthreads();
    const float* wlv = wl + zsh;             // runtime ==wl; VGPR addressing

    int w = Lw;
#pragma unroll
    for (int s = 0; s < 5; ++s) {
        const int d  = 1 << s;
        const int nw = w - d;
        const bool a0 = (tx < nw);
        const bool a1 = (64 + tx < nw);
        const int p0 = a0 ? tx : 0;          // clamped: in-bounds garbage
        const int p1 = a1 ? (64 + tx) : 0;
        const float* wb0 = wlv + s * 5120;   // wf[ic*64+k*32+oc] | wg +2048 | wr +4096

        // residual taps X[p+d], preloaded (X overwritten post-barrier)
        float t0[4], t1[4];
#pragma unroll
        for (int j = 0; j < 4; ++j) {
            t0[j] = Xs[(oc0 + j) * 128 + p0 + d];
            t1[j] = Xs[(oc0 + j) * 128 + p1 + d];
        }

        float f0[4], g0[4], f1[4], g1[4];
#pragma unroll
        for (int j = 0; j < 4; ++j) { f0[j]=0.f; g0[j]=0.f; f1[j]=0.f; g1[j]=0.f; }
#pragma unroll 4
        for (int ic = 0; ic < 32; ++ic) {
            const float4 wa = *(const float4*)(wb0 + ic * 64 + oc0);
            const float4 wc = *(const float4*)(wb0 + ic * 64 + 32 + oc0);
            const float4 ga = *(const float4*)(wb0 + 2048 + ic * 64 + oc0);
            const float4 gc = *(const float4*)(wb0 + 2048 + ic * 64 + 32 + oc0);
            const float wa_[4] = {wa.x, wa.y, wa.z, wa.w};
            const float wc_[4] = {wc.x, wc.y, wc.z, wc.w};
            const float ga_[4] = {ga.x, ga.y, ga.z, ga.w};
            const float gc_[4] = {gc.x, gc.y, gc.z, gc.w};
            const float a0v = Xs[ic * 128 + p0];
            const float c0v = Xs[ic * 128 + p0 + d];
            const float a1v = Xs[ic * 128 + p1];
            const float c1v = Xs[ic * 128 + p1 + d];
#pragma unroll
            for (int j = 0; j < 4; ++j) {        // per-acc order: a then c, ic asc
                f0[j] = fmaf(wa_[j], a0v, f0[j]);
                f0[j] = fmaf(wc_[j], c0v, f0[j]);
                g0[j] = fmaf(ga_[j], a0v, g0[j]);
                g0[j] = fmaf(gc_[j], c0v, g0[j]);
                f1[j] = fmaf(wa_[j], a1v, f1[j]);
                f1[j] = fmaf(wc_[j], c1v, f1[j]);
                g1[j] = fmaf(ga_[j], a1v, g1[j]);
                g1[j] = fmaf(gc_[j], c1v, g1[j]);
            }
        }
        float h0[4], h1[4];
#pragma unroll
        for (int j = 0; j < 4; ++j) {
            h0[j] = tanh_fast(f0[j]) * sigmoid_fast(g0[j]);
            h1[j] = tanh_fast(f1[j]) * sigmoid_fast(g1[j]);
        }

        if (MODE == 2 && s == 4) {               // layer 39: h only, reg-direct
            if (a0) {
                float* dst = outp + (size_t)b * 262144 + (size_t)(((c0 + tx) << 5) + r);
#pragma unroll
                for (int j = 0; j < 4; ++j) dst[(size_t)(oc0 + j) * 8192] = h0[j];
            }
            if (a1) {
                float* dst = outp + (size_t)b * 262144 + (size_t)(((c0 + 64 + tx) << 5) + r);
#pragma unroll
                for (int j = 0; j < 4; ++j) dst[(size_t)(oc0 + j) * 8192] = h1[j];
            }
            return;
        }

        if (a0) {
#pragma unroll
            for (int j = 0; j < 4; ++j) Hs[(oc0 + j) * 128 + tx] = h0[j];
        }
        if (a1) {
#pragma unroll
            for (int j = 0; j < 4; ++j) Hs[(oc0 + j) * 128 + 64 + tx] = h1[j];
        }
        __syncthreads();   // X reads + H writes complete (per-thread lgkmcnt(0))

        float r0[4], r1[4];
#pragma unroll
        for (int j = 0; j < 4; ++j) { r0[j] = t0[j]; r1[j] = t1[j]; }
#pragma unroll 4
        for (int ic = 0; ic < 32; ++ic) {
            const float4 wv = *(const float4*)(wb0 + 4096 + ic * 32 + oc0);
            const float wv_[4] = {wv.x, wv.y, wv.z, wv.w};
            const float h0v = Hs[ic * 128 + p0];
            const float h1v = Hs[ic * 128 + p1];
#pragma unroll
            for (int j = 0; j < 4; ++j) {
                r0[j] = fmaf(wv_[j], h0v, r0[j]);
                r1[j] = fmaf(wv_[j], h1v, r1[j]);
            }
        }

        if (s == 4) {                            // final: reg-direct global store
            if (MODE == 0) {                     // -> Xsub[b][oc][t&31][t>>5]
                if (a0) {
                    const int t = c0 + tx;
                    float* dst = outp + (size_t)b * 262144 + (size_t)(t & 31) * 256 + (t >> 5);
#pragma unroll
                    for (int j = 0; j < 4; ++j) dst[(size_t)(oc0 + j) * 8192] = r0[j];
                }
                if (a1) {
                    const int t = c0 + 64 + tx;
                    float* dst = outp + (size_t)b * 262144 + (size_t)(t & 31) * 256 + (t >> 5);
#pragma unroll
                    for (int j = 0; j < 4; ++j) dst[(size_t)(oc0 + j) * 8192] = r1[j];
                }
            } else {                             // -> X[b][oc][32*p + r]
                if (a0) {
                    float* dst = outp + (size_t)b * 262144 + (size_t)(((c0 + tx) << 5) + r);
#pragma unroll
                    for (int j = 0; j < 4; ++j) dst[(size_t)(oc0 + j) * 8192] = r0[j];
                }
                if (a1) {
                    float* dst = outp + (size_t)b * 262144 + (size_t)(((c0 + 64 + tx) << 5) + r);
#pragma unroll
                    for (int j = 0; j < 4; ++j) dst[(size_t)(oc0 + j) * 8192] = r1[j];
                }
            }
        } else {                                 // in-place X update
            if (a0) {
#pragma unroll
                for (int j = 0; j < 4; ++j) Xs[(oc0 + j) * 128 + tx] = r0[j];
            }
            if (a1) {
#pragma unroll
                for (int j = 0; j < 4; ++j) Xs[(oc0 + j) * 128 + 64 + tx] = r1[j];
            }
            __syncthreads();                     // X writes visible for next layer
        }
        w = nw;
    }
}

// ---------------------------------------------------------------------------
// skip conv + relu, 32 outputs/thread; weights vector-loaded (vz trick)
__global__ __launch_bounds__(256) void skip_kernel(const float* __restrict__ xin,
                                                   const float* __restrict__ sk,
                                                   float* __restrict__ h1) {
    __shared__ int zs;
    if (threadIdx.x == 0) zs = 0;
    __syncthreads();
    const int vz = zs;
    int t = blockIdx.x * 256 + threadIdx.x;
    int sg = blockIdx.y;                     // 8 groups of 32
    int b = blockIdx.z;
    const float* xi = xin + (size_t)(b * RCH) * TS + t;
    const float* wb = sk + vz + sg * 32;
    float acc[32];
#pragma unroll
    for (int j = 0; j < 32; j++) acc[j] = 0.f;
#pragma unroll 4
    for (int dc = 0; dc < 32; dc++) {
        float xv = xi[dc * TS];
        const float* w = wb + dc * 256;
#pragma unroll
        for (int q = 0; q < 8; q++) {
            const float4 w4 = *(const float4*)(w + q * 4);
            acc[q*4+0] = fmaf(w4.x, xv, acc[q*4+0]);
            acc[q*4+1] = fmaf(w4.y, xv, acc[q*4+1]);
            acc[q*4+2] = fmaf(w4.z, xv, acc[q*4+2]);
            acc[q*4+3] = fmaf(w4.w, xv, acc[q*4+3]);
        }
    }
    float* ho = h1 + ((size_t)(b * 256) + sg * 32) * TOUT + t;
#pragma unroll
    for (int j = 0; j < 32; j++) ho[j * TOUT] = fmaxf(acc[j], 0.f);
}

// end1 + bias + relu, 32 outputs/thread; weights vector-loaded
__global__ __launch_bounds__(256) void end1_kernel(const float* __restrict__ h1,
                                                   const float* __restrict__ e1t,
                                                   const float* __restrict__ b1,
                                                   float* __restrict__ e1) {
    __shared__ int zs;
    if (threadIdx.x == 0) zs = 0;
    __syncthreads();
    const int vz = zs;
    int t = blockIdx.x * 256 + threadIdx.x;
    int eg = blockIdx.y;                     // 8 groups of 32
    int b = blockIdx.z;
    const float* hp = h1 + (size_t)(b * 256) * TOUT + t;
    const float* wb = e1t + vz + eg * 32;
    float acc[32];
#pragma unroll
    for (int j = 0; j < 32; j++) acc[j] = b1[eg * 32 + j];
#pragma unroll 4
    for (int sc = 0; sc < 256; sc++) {
        float xv = hp[sc * TOUT];
        const float* w = wb + sc * 256;
#pragma unroll
        for (int q = 0; q < 8; q++) {
            const float4 w4 = *(const float4*)(w + q * 4);
            acc[q*4+0] = fmaf(w4.x, xv, acc[q*4+0]);
            acc[q*4+1] = fmaf(w4.y, xv, acc[q*4+1]);
            acc[q*4+2] = fmaf(w4.z, xv, acc[q*4+2]);
            acc[q*4+3] = fmaf(w4.w, xv, acc[q*4+3]);
        }
    }
    float* ep = e1 + ((size_t)(b * 256) + eg * 32) * TOUT + t;
#pragma unroll
    for (int j = 0; j < 32; j++) ep[j * TOUT] = fmaxf(acc[j], 0.f);
}

// end2 + bias, transposed store, 32 outputs/thread; weights vector-loaded
__global__ __launch_bounds__(256) void end2_kernel(const float* __restrict__ e1,
                                                   const float* __restrict__ e2t,
                                                   const float* __restrict__ b2,
                                                   float* __restrict__ out) {
    __shared__ int zs;
    if (threadIdx.x == 0) zs = 0;
    __syncthreads();
    const int vz = zs;
    int t = blockIdx.x * 256 + threadIdx.x;
    int cg = blockIdx.y;                     // 8 groups of 32
    int b = blockIdx.z;
    const float* ep = e1 + (size_t)(b * 256) * TOUT + t;
    const float* wb = e2t + vz + cg * 32;
    float acc[32];
#pragma unroll
    for (int j = 0; j < 32; j++) acc[j] = b2[cg * 32 + j];
#pragma unroll 4
    for (int ec = 0; ec < 256; ec++) {
        float xv = ep[ec * TOUT];
        const float* w = wb + ec * 256;
#pragma unroll
        for (int q = 0; q < 8; q++) {
            const float4 w4 = *(const float4*)(w + q * 4);
            acc[q*4+0] = fmaf(w4.x, xv, acc[q*4+0]);
            acc[q*4+1] = fmaf(w4.y, xv, acc[q*4+1]);
            acc[q*4+2] = fmaf(w4.z, xv, acc[q*4+2]);
            acc[q*4+3] = fmaf(w4.w, xv, acc[q*4+3]);
        }
    }
    float* op = out + ((size_t)(b * TOUT + t)) * CLS + cg * 32;
#pragma unroll
    for (int j = 0; j < 8; j++)
        ((float4*)op)[j] = make_float4(acc[4*j], acc[4*j+1], acc[4*j+2], acc[4*j+3]);
}

// ---------------------------------------------------------------------------
extern "C" void kernel_launch(void* const* d_in, const int* in_sizes, int n_in,
                              void* d_out, int out_size, void* d_ws, size_t ws_size,
                              hipStream_t stream) {
    const float* x_input    = (const float*)d_in[0];
    const float* start_w    = (const float*)d_in[1];
    const float* filter_w   = (const float*)d_in[2];
    const float* gate_w     = (const float*)d_in[3];
    const float* residual_w = (const float*)d_in[4];
    const float* skip_w     = (const float*)d_in[5];
    const float* end1_w     = (const float*)d_in[6];
    const float* end1_b     = (const float*)d_in[7];
    const float* end2_w     = (const float*)d_in[8];
    const float* end2_b     = (const float*)d_in[9];
    float* ws  = (float*)d_ws;
    float* out = (float*)d_out;

    repack_kernel<<<dim3((352256 + 255) / 256), 256, 0, stream>>>(
        start_w, filter_w, gate_w, residual_w, skip_w, end1_w, end2_w, ws);

    start_kernel<<<dim3(32, 2, NB), 256, 0, stream>>>(
        x_input, ws + OFF_ST, ws + OFF_XA);

    float* xa   = ws + OFF_XA;
    float* xsub = ws + OFF_XSUB;
    int Tin = T0;                            // 8188
    for (int sb = 0; sb < 4; ++sb) {
        const float* wb = ws + OFF_WBLOB + (size_t)sb * 51200;
        const int Th  = Tin - 31;            // head output length
        const int nbh = (Th + 95) / 96;
        five_kernel<0><<<dim3(nbh, NB), dim3(64, 8), 0, stream>>>(xa, xsub, wb, Tin);

        const int Lmax  = (Th + 31) >> 5;    // longest residue subsequence
        const int LoutM = Lmax - 31;
        const int nbt   = (LoutM + 95) / 96;
        if (sb < 3)
            five_kernel<1><<<dim3(nbt, 32, NB), dim3(64, 8), 0, stream>>>(xsub, xa, wb + 25600, Th);
        else
            five_kernel<2><<<dim3(nbt, 32, NB), dim3(64, 8), 0, stream>>>(xsub, xa, wb + 25600, Th);
        Tin = Th - 992;
    }
    // Tin == 4096; layer-39 h in xa

    skip_kernel<<<dim3(16, 8, NB), 256, 0, stream>>>(xa, ws + OFF_SK, ws + OFF_H1);
    end1_kernel<<<dim3(16, 8, NB), 256, 0, stream>>>(ws + OFF_H1, ws + OFF_E1T, end1_b, ws + OFF_E1);
    end2_kernel<<<dim3(16, 8, NB), 256, 0, stream>>>(ws + OFF_E1, ws + OFF_E2T, end2_b, out);
}

// Round 6
// 863.826 us; speedup vs baseline: 7.6843x; 1.0307x over previous
//
#include <hip/hip_runtime.h>
#include <math.h>

// ---------------------------------------------------------------------------
// WaveNet inference, fp32, right-aligned suffix computation.
// Round 9: LDS-pipe reduction. Rounds 7/8 tied (97us, VALUBusy 50%) across
// two different weight paths -> weights not binding; accounting shows ~216
// b32 LDS insts/thread-layer ~= 54us/CU of LDS-pipe occupancy = the limiter.
// Now thread owns CONSECUTIVE positions (p=2tx,2tx+1): all X/H LDS traffic
// becomes float2 (ds_*_b64), ~112 insts/thread-layer. d=1 taps composed from
// two aligned b64 (d constexpr per unrolled layer). Widths 144/130 make all
// LDS accesses in-bounds for any tx -> compute unpredicated (garbage beyond
// nw is dead: layer s+1 reads only [0, nw(s+1)-1+d] = [0, nw(s)-1]); only
// global stores predicated per position.
// FP order per output identical to rounds 5-8 -> absmax must stay 2.4e-4.
// Chain: 8188 -h-> 8157 -t-> 7165 -h-> 7134 -t-> 6142 -h-> 6111 -t-> 5119
//        -h-> 5088 -t-> 4096.  Layer 39 (last tail, s=4) emits h only.
// ---------------------------------------------------------------------------

#define TS   8192
#define T0   8188
#define NB   8
#define RCH  32
#define CLS  256
#define TOUT 4096

// workspace layout (float offsets)
#define OFF_WBLOB 0                      // 40 * 5120  (wf[ic][k][oc], wg, wr[ic][oc])
#define OFF_ST    204800                 // start_w^T  [ic][oc]
#define OFF_SK    212992                 // skip_w[39]^T [dc][sc]
#define OFF_E1T   221184                 // end1^T [sc][ec]
#define OFF_E2T   286720                 // end2^T [ec][cc]
#define OFF_XA    352256                 // NB*RCH*TS   (normal layout)
#define OFF_XSUB  (OFF_XA + NB*RCH*TS)   // NB*32*32*256 (sub layout)
#define OFF_H1    (OFF_XSUB + NB*RCH*TS) // NB*256*TOUT
#define OFF_E1    (OFF_H1 + NB*256*TOUT)

#define XW 144                           // Xs row stride (max read idx 143)
#define HW 130                           // Hs row stride

__device__ __forceinline__ float tanh_fast(float x) {
    float e = __expf(2.0f * x);
    return 1.0f - 2.0f / (e + 1.0f);
}
__device__ __forceinline__ float sigmoid_fast(float x) {
    return 1.0f / (1.0f + __expf(-x));
}

// ---------------------------------------------------------------------------
__global__ void repack_kernel(const float* __restrict__ start_w,
                              const float* __restrict__ filter_w,
                              const float* __restrict__ gate_w,
                              const float* __restrict__ residual_w,
                              const float* __restrict__ skip_w,
                              const float* __restrict__ end1_w,
                              const float* __restrict__ end2_w,
                              float* __restrict__ ws) {
    int id = blockIdx.x * 256 + threadIdx.x;
    if (id < 204800) {
        int l = id / 5120, r = id % 5120;
        float v;
        if (r < 4096) {                      // wf then wg: [ic][k][oc]
            const float* src = (r < 2048) ? filter_w : gate_w;
            int rr = r & 2047;
            int ic = rr >> 6, k = (rr >> 5) & 1, oc = rr & 31;
            v = src[((l * 32 + oc) * 32 + ic) * 2 + k];
        } else {                             // wr: [ic][oc]
            int rr = r - 4096;
            int ic = rr >> 5, oc = rr & 31;
            v = residual_w[(l * 32 + oc) * 32 + ic];
        }
        ws[OFF_WBLOB + id] = v;
    } else if (id < 204800 + 8192) {
        int r = id - 204800;
        int ic = r >> 5, oc = r & 31;
        ws[OFF_ST + r] = start_w[oc * 256 + ic];
    } else if (id < 212992 + 8192) {
        int r = id - 212992;
        int dc = r >> 8, sc = r & 255;
        ws[OFF_SK + r] = skip_w[(39 * 256 + sc) * 32 + dc];
    } else if (id < 221184 + 65536) {
        int r = id - 221184;
        int sc = r >> 8, ec = r & 255;
        ws[OFF_E1T + r] = end1_w[ec * 256 + sc];
    } else if (id < 286720 + 65536) {
        int r = id - 286720;
        int ec = r >> 8, cc = r & 255;
        ws[OFF_E2T + r] = end2_w[cc * 256 + ec];
    }
}

// ---------------------------------------------------------------------------
// start conv, 16 outputs/thread; weights vector-loaded (vz trick)
__global__ __launch_bounds__(256) void start_kernel(const float* __restrict__ xin,
                                                    const float* __restrict__ st,
                                                    float* __restrict__ xout) {
    __shared__ int zs;
    if (threadIdx.x == 0) zs = 0;
    __syncthreads();
    const int vz = zs;                       // runtime 0, compiler-opaque
    int t = blockIdx.x * 256 + threadIdx.x;
    int og = blockIdx.y;                     // 0..1 (16 oc each)
    int b = blockIdx.z;
    if (t >= T0) return;
    const float* xi = xin + (size_t)b * 256 * 16384 + (16384 - T0) + t;
    const float* wb = st + vz + og * 16;
    float acc[16];
#pragma unroll
    for (int c = 0; c < 16; c++) acc[c] = 0.f;
#pragma unroll 4
    for (int ic = 0; ic < 256; ic++) {
        float xv = xi[ic * 16384];
        const float* w = wb + ic * 32;
        const float4 w0 = *(const float4*)(w);
        const float4 w1 = *(const float4*)(w + 4);
        const float4 w2 = *(const float4*)(w + 8);
        const float4 w3 = *(const float4*)(w + 12);
        const float ww[16] = {w0.x,w0.y,w0.z,w0.w, w1.x,w1.y,w1.z,w1.w,
                              w2.x,w2.y,w2.z,w2.w, w3.x,w3.y,w3.z,w3.w};
#pragma unroll
        for (int c = 0; c < 16; c++) acc[c] = fmaf(ww[c], xv, acc[c]);
    }
    float* xo = xout + ((size_t)(b * RCH) + og * 16) * TS + t;
#pragma unroll
    for (int c = 0; c < 16; c++) xo[c * TS] = acc[c];
}

// ---------------------------------------------------------------------------
// 5 fused layers (dil 1,2,4,8,16). Block (64,8): wave = 4-oc group, 96 output
// positions/block (tile 127). Thread = positions 2tx, 2tx+1 (consecutive ->
// b64 LDS ops). Single in-place X buffer: all X reads pre-barrier, X writes
// post-barrier. Weights via global_load_dwordx4 (vz trick, L1-resident).
// MODE 0: head (X normal -> Xsub). MODE 1: tail (Xsub -> X).
// MODE 2: tail-last (layer s=4 emits h only).
template<int MODE>
__global__ __launch_bounds__(512, 4) void five_kernel(const float* __restrict__ in,
                                                      float* __restrict__ outp,
                                                      const float* __restrict__ wl,
                                                      int Tin) {
    __shared__ float Xs[32 * XW];
    __shared__ float Hs[32 * HW];
    __shared__ int zsh;
    const int tx  = threadIdx.x;
    const int cg  = __builtin_amdgcn_readfirstlane(threadIdx.y);   // 0..7
    const int oc0 = cg * 4;
    const int c0  = blockIdx.x * 96;
    const int b   = (MODE == 0) ? blockIdx.y : blockIdx.z;
    const int r   = (MODE == 0) ? 0 : blockIdx.y;
    const int L   = (MODE == 0) ? Tin : ((Tin - r + 31) >> 5);
    const int Lw  = min(127, L - c0);
    const int px  = tx * 2;                  // positions px, px+1

    if (tx == 0 && threadIdx.y == 0) zsh = 0;

    // coalesced tile load (head: stride-1 in t; tail: stride-1 in subseq idx)
    const float* src = in + (size_t)b * 262144 + (size_t)r * 256 + c0;
    for (int ch = cg; ch < 32; ch += 8)
        for (int p = tx; p < Lw; p += 64)
            Xs[ch * XW + p] = src[(size_t)ch * 8192 + p];
    __syncthreads();
    const float* wlv = wl + zsh;             // runtime ==wl; VGPR addressing

    int w = Lw;
#pragma unroll
    for (int s = 0; s < 5; ++s) {
        const int d  = 1 << s;               // constexpr per unrolled iter
        const int nw = w - d;
        const float* wb0 = wlv + s * 5120;   // wf[ic*64+k*32+oc] | wg +2048 | wr +4096

        // residual taps X[p+d] for own 4 oc, both positions (pre-barrier)
        float tA[4], tB[4];
        if (!(MODE == 2 && s == 4)) {
#pragma unroll
            for (int j = 0; j < 4; ++j) {
                const float* xr = Xs + (oc0 + j) * XW + px;
                if (d == 1) {
                    const float2 u = *(const float2*)(xr);
                    const float2 v = *(const float2*)(xr + 2);
                    tA[j] = u.y; tB[j] = v.x;
                } else {
                    const float2 u = *(const float2*)(xr + d);  // d even: aligned
                    tA[j] = u.x; tB[j] = u.y;
                }
            }
        }

        float f0[4], g0[4], f1[4], g1[4];
#pragma unroll
        for (int j = 0; j < 4; ++j) { f0[j]=0.f; g0[j]=0.f; f1[j]=0.f; g1[j]=0.f; }
#pragma unroll 4
        for (int ic = 0; ic < 32; ++ic) {
            const float* xr = Xs + ic * XW + px;
            const float2 a2 = *(const float2*)(xr);             // a-taps both pos
            float2 c2;
            if (d == 1) {
                const float2 b2 = *(const float2*)(xr + 2);
                c2.x = a2.y; c2.y = b2.x;
            } else {
                c2 = *(const float2*)(xr + d);                  // aligned b64
            }
            const float4 wa = *(const float4*)(wb0 + ic * 64 + oc0);
            const float4 wc = *(const float4*)(wb0 + ic * 64 + 32 + oc0);
            const float4 ga = *(const float4*)(wb0 + 2048 + ic * 64 + oc0);
            const float4 gc = *(const float4*)(wb0 + 2048 + ic * 64 + 32 + oc0);
            const float wa_[4] = {wa.x, wa.y, wa.z, wa.w};
            const float wc_[4] = {wc.x, wc.y, wc.z, wc.w};
            const float ga_[4] = {ga.x, ga.y, ga.z, ga.w};
            const float gc_[4] = {gc.x, gc.y, gc.z, gc.w};
#pragma unroll
            for (int j = 0; j < 4; ++j) {        // per-acc order: a then c, ic asc
                f0[j] = fmaf(wa_[j], a2.x, f0[j]);
                f0[j] = fmaf(wc_[j], c2.x, f0[j]);
                g0[j] = fmaf(ga_[j], a2.x, g0[j]);
                g0[j] = fmaf(gc_[j], c2.x, g0[j]);
                f1[j] = fmaf(wa_[j], a2.y, f1[j]);
                f1[j] = fmaf(wc_[j], c2.y, f1[j]);
                g1[j] = fmaf(ga_[j], a2.y, g1[j]);
                g1[j] = fmaf(gc_[j], c2.y, g1[j]);
            }
        }
        float h0[4], h1[4];
#pragma unroll
        for (int j = 0; j < 4; ++j) {
            h0[j] = tanh_fast(f0[j]) * sigmoid_fast(g0[j]);
            h1[j] = tanh_fast(f1[j]) * sigmoid_fast(g1[j]);
        }

        if (MODE == 2 && s == 4) {               // layer 39: h only, reg-direct
            if (px < nw) {
                float* dst = outp + (size_t)b * 262144 + (size_t)(((c0 + px) << 5) + r);
#pragma unroll
                for (int j = 0; j < 4; ++j) dst[(size_t)(oc0 + j) * 8192] = h0[j];
            }
            if (px + 1 < nw) {
                float* dst = outp + (size_t)b * 262144 + (size_t)(((c0 + px + 1) << 5) + r);
#pragma unroll
                for (int j = 0; j < 4; ++j) dst[(size_t)(oc0 + j) * 8192] = h1[j];
            }
            return;
        }

        // Hs write (unpredicated: positions >= nw are dead garbage)
#pragma unroll
        for (int j = 0; j < 4; ++j)
            *(float2*)(Hs + (oc0 + j) * HW + px) = make_float2(h0[j], h1[j]);
        __syncthreads();   // all X reads + H writes complete

        float r0[4], r1[4];
#pragma unroll
        for (int j = 0; j < 4; ++j) { r0[j] = tA[j]; r1[j] = tB[j]; }
#pragma unroll 4
        for (int ic = 0; ic < 32; ++ic) {
            const float2 h2 = *(const float2*)(Hs + ic * HW + px);
            const float4 wv = *(const float4*)(wb0 + 4096 + ic * 32 + oc0);
            const float wv_[4] = {wv.x, wv.y, wv.z, wv.w};
#pragma unroll
            for (int j = 0; j < 4; ++j) {
                r0[j] = fmaf(wv_[j], h2.x, r0[j]);
                r1[j] = fmaf(wv_[j], h2.y, r1[j]);
            }
        }

        if (s == 4) {                            // final: reg-direct global store
            if (MODE == 0) {                     // -> Xsub[b][oc][t&31][t>>5]
                if (px < nw) {
                    const int t = c0 + px;
                    float* dst = outp + (size_t)b * 262144 + (size_t)(t & 31) * 256 + (t >> 5);
#pragma unroll
                    for (int j = 0; j < 4; ++j) dst[(size_t)(oc0 + j) * 8192] = r0[j];
                }
                if (px + 1 < nw) {
                    const int t = c0 + px + 1;
                    float* dst = outp + (size_t)b * 262144 + (size_t)(t & 31) * 256 + (t >> 5);
#pragma unroll
                    for (int j = 0; j < 4; ++j) dst[(size_t)(oc0 + j) * 8192] = r1[j];
                }
            } else {                             // -> X[b][oc][32*p + r]
                if (px < nw) {
                    float* dst = outp + (size_t)b * 262144 + (size_t)(((c0 + px) << 5) + r);
#pragma unroll
                    for (int j = 0; j < 4; ++j) dst[(size_t)(oc0 + j) * 8192] = r0[j];
                }
                if (px + 1 < nw) {
                    float* dst = outp + (size_t)b * 262144 + (size_t)(((c0 + px + 1) << 5) + r);
#pragma unroll
                    for (int j = 0; j < 4; ++j) dst[(size_t)(oc0 + j) * 8192] = r1[j];
                }
            }
        } else {                                 // in-place X update (b64)
#pragma unroll
            for (int j = 0; j < 4; ++j)
                *(float2*)(Xs + (oc0 + j) * XW + px) = make_float2(r0[j], r1[j]);
            __syncthreads();                     // X writes visible for next layer
        }
        w = nw;
    }
}

// ---------------------------------------------------------------------------
// skip conv + relu, 32 outputs/thread; weights vector-loaded (vz trick)
__global__ __launch_bounds__(256) void skip_kernel(const float* __restrict__ xin,
                                                   const float* __restrict__ sk,
                                                   float* __restrict__ h1) {
    __shared__ int zs;
    if (threadIdx.x == 0) zs = 0;
    __syncthreads();
    const int vz = zs;
    int t = blockIdx.x * 256 + threadIdx.x;
    int sg = blockIdx.y;                     // 8 groups of 32
    int b = blockIdx.z;
    const float* xi = xin + (size_t)(b * RCH) * TS + t;
    const float* wb = sk + vz + sg * 32;
    float acc[32];
#pragma unroll
    for (int j = 0; j < 32; j++) acc[j] = 0.f;
#pragma unroll 4
    for (int dc = 0; dc < 32; dc++) {
        float xv = xi[dc * TS];
        const float* w = wb + dc * 256;
#pragma unroll
        for (int q = 0; q < 8; q++) {
            const float4 w4 = *(const float4*)(w + q * 4);
            acc[q*4+0] = fmaf(w4.x, xv, acc[q*4+0]);
            acc[q*4+1] = fmaf(w4.y, xv, acc[q*4+1]);
            acc[q*4+2] = fmaf(w4.z, xv, acc[q*4+2]);
            acc[q*4+3] = fmaf(w4.w, xv, acc[q*4+3]);
        }
    }
    float* ho = h1 + ((size_t)(b * 256) + sg * 32) * TOUT + t;
#pragma unroll
    for (int j = 0; j < 32; j++) ho[j * TOUT] = fmaxf(acc[j], 0.f);
}

// end1 + bias + relu, 32 outputs/thread; weights vector-loaded
__global__ __launch_bounds__(256) void end1_kernel(const float* __restrict__ h1,
                                                   const float* __restrict__ e1t,
                                                   const float* __restrict__ b1,
                                                   float* __restrict__ e1) {
    __shared__ int zs;
    if (threadIdx.x == 0) zs = 0;
    __syncthreads();
    const int vz = zs;
    int t = blockIdx.x * 256 + threadIdx.x;
    int eg = blockIdx.y;                     // 8 groups of 32
    int b = blockIdx.z;
    const float* hp = h1 + (size_t)(b * 256) * TOUT + t;
    const float* wb = e1t + vz + eg * 32;
    float acc[32];
#pragma unroll
    for (int j = 0; j < 32; j++) acc[j] = b1[eg * 32 + j];
#pragma unroll 4
    for (int sc = 0; sc < 256; sc++) {
        float xv = hp[sc * TOUT];
        const float* w = wb + sc * 256;
#pragma unroll
        for (int q = 0; q < 8; q++) {
            const float4 w4 = *(const float4*)(w + q * 4);
            acc[q*4+0] = fmaf(w4.x, xv, acc[q*4+0]);
            acc[q*4+1] = fmaf(w4.y, xv, acc[q*4+1]);
            acc[q*4+2] = fmaf(w4.z, xv, acc[q*4+2]);
            acc[q*4+3] = fmaf(w4.w, xv, acc[q*4+3]);
        }
    }
    float* ep = e1 + ((size_t)(b * 256) + eg * 32) * TOUT + t;
#pragma unroll
    for (int j = 0; j < 32; j++) ep[j * TOUT] = fmaxf(acc[j], 0.f);
}

// end2 + bias, transposed store, 32 outputs/thread; weights vector-loaded
__global__ __launch_bounds__(256) void end2_kernel(const float* __restrict__ e1,
                                                   const float* __restrict__ e2t,
                                                   const float* __restrict__ b2,
                                                   float* __restrict__ out) {
    __shared__ int zs;
    if (threadIdx.x == 0) zs = 0;
    __syncthreads();
    const int vz = zs;
    int t = blockIdx.x * 256 + threadIdx.x;
    int cg = blockIdx.y;                     // 8 groups of 32
    int b = blockIdx.z;
    const float* ep = e1 + (size_t)(b * 256) * TOUT + t;
    const float* wb = e2t + vz + cg * 32;
    float acc[32];
#pragma unroll
    for (int j = 0; j < 32; j++) acc[j] = b2[cg * 32 + j];
#pragma unroll 4
    for (int ec = 0; ec < 256; ec++) {
        float xv = ep[ec * TOUT];
        const float* w = wb + ec * 256;
#pragma unroll
        for (int q = 0; q < 8; q++) {
            const float4 w4 = *(const float4*)(w + q * 4);
            acc[q*4+0] = fmaf(w4.x, xv, acc[q*4+0]);
            acc[q*4+1] = fmaf(w4.y, xv, acc[q*4+1]);
            acc[q*4+2] = fmaf(w4.z, xv, acc[q*4+2]);
            acc[q*4+3] = fmaf(w4.w, xv, acc[q*4+3]);
        }
    }
    float* op = out + ((size_t)(b * TOUT + t)) * CLS + cg * 32;
#pragma unroll
    for (int j = 0; j < 8; j++)
        ((float4*)op)[j] = make_float4(acc[4*j], acc[4*j+1], acc[4*j+2], acc[4*j+3]);
}

// ---------------------------------------------------------------------------
extern "C" void kernel_launch(void* const* d_in, const int* in_sizes, int n_in,
                              void* d_out, int out_size, void* d_ws, size_t ws_size,
                              hipStream_t stream) {
    const float* x_input    = (const float*)d_in[0];
    const float* start_w    = (const float*)d_in[1];
    const float* filter_w   = (const float*)d_in[2];
    const float* gate_w     = (const float*)d_in[3];
    const float* residual_w = (const float*)d_in[4];
    const float* skip_w     = (const float*)d_in[5];
    const float* end1_w     = (const float*)d_in[6];
    const float* end1_b     = (const float*)d_in[7];
    const float* end2_w     = (const float*)d_in[8];
    const float* end2_b     = (const float*)d_in[9];
    float* ws  = (float*)d_ws;
    float* out = (float*)d_out;

    repack_kernel<<<dim3((352256 + 255) / 256), 256, 0, stream>>>(
        start_w, filter_w, gate_w, residual_w, skip_w, end1_w, end2_w, ws);

    start_kernel<<<dim3(32, 2, NB), 256, 0, stream>>>(
        x_input, ws + OFF_ST, ws + OFF_XA);

    float* xa   = ws + OFF_XA;
    float* xsub = ws + OFF_XSUB;
    int Tin = T0;                            // 8188
    for (int sb = 0; sb < 4; ++sb) {
        const float* wb = ws + OFF_WBLOB + (size_t)sb * 51200;
        const int Th  = Tin - 31;            // head output length
        const int nbh = (Th + 95) / 96;
        five_kernel<0><<<dim3(nbh, NB), dim3(64, 8), 0, stream>>>(xa, xsub, wb, Tin);

        const int Lmax  = (Th + 31) >> 5;    // longest residue subsequence
        const int LoutM = Lmax - 31;
        const int nbt   = (LoutM + 95) / 96;
        if (sb < 3)
            five_kernel<1><<<dim3(nbt, 32, NB), dim3(64, 8), 0, stream>>>(xsub, xa, wb + 25600, Th);
        else
            five_kernel<2><<<dim3(nbt, 32, NB), dim3(64, 8), 0, stream>>>(xsub, xa, wb + 25600, Th);
        Tin = Th - 992;
    }
    // Tin == 4096; layer-39 h in xa

    skip_kernel<<<dim3(16, 8, NB), 256, 0, stream>>>(xa, ws + OFF_SK, ws + OFF_H1);
    end1_kernel<<<dim3(16, 8, NB), 256, 0, stream>>>(ws + OFF_H1, ws + OFF_E1T, end1_b, ws + OFF_E1);
    end2_kernel<<<dim3(16, 8, NB), 256, 0, stream>>>(ws + OFF_E1, ws + OFF_E2T, end2_b, out);
}